// Round 4
// baseline (2282.195 us; speedup 1.0000x reference)
//
#include <hip/hip_runtime.h>
#include <stdint.h>

using short8  = __attribute__((ext_vector_type(8))) short;
using floatx4 = __attribute__((ext_vector_type(4))) float;

typedef unsigned short u16;
typedef unsigned int u32;
typedef unsigned long long u64;

#define AS1(p) ((const __attribute__((address_space(1))) void*)(p))
#define AS3(p) ((__attribute__((address_space(3))) void*)(p))

__device__ __forceinline__ float bs2f(u16 u) { return __uint_as_float(((u32)u) << 16); }
__device__ __forceinline__ u16 f2bs(float f) {
  u32 x = __float_as_uint(f);
  x += 0x7FFFu + ((x >> 16) & 1u);   // RNE
  return (u16)(x >> 16);
}
__device__ __forceinline__ float lo16(u32 u) { return __uint_as_float(u << 16); }
__device__ __forceinline__ float hi16(u32 u) { return __uint_as_float(u & 0xFFFF0000u); }

// ---------------------------------------------------------------------------
// fp32 -> bf16 weight conversion (RNE)
// ---------------------------------------------------------------------------
__global__ __launch_bounds__(256) void cvt_k(const float* __restrict__ src,
                                             u16* __restrict__ dst, int n) {
  int i = blockIdx.x * 256 + threadIdx.x;
  if (i < n) dst[i] = f2bs(src[i]);
}

// ---------------------------------------------------------------------------
// LIF reservoir: 32 blocks (1/batch) x 512 threads (1/neuron), exact fp32.
// rec[r] = z @ Wres[:,r] maintained incrementally from per-wave change masks.
// ONE barrier per step; z staged in double-buffered LDS (2x16 steps) and
// flushed every 16 steps with coalesced dwordx4 stores, so no per-step
// vmcnt(0) drain at the barrier.
// ---------------------------------------------------------------------------
__device__ __forceinline__ float gather4(const float* __restrict__ Wcol, u64 m, int base) {
  float s0 = 0.f, s1 = 0.f, s2 = 0.f, s3 = 0.f;
  while (m) {
    int i0 = __builtin_ctzll(m); m &= m - 1;
    s0 += Wcol[(size_t)(base + i0) << 9];
    if (m) { int i1 = __builtin_ctzll(m); m &= m - 1; s1 += Wcol[(size_t)(base + i1) << 9]; }
    if (m) { int i2 = __builtin_ctzll(m); m &= m - 1; s2 += Wcol[(size_t)(base + i2) << 9]; }
    if (m) { int i3 = __builtin_ctzll(m); m &= m - 1; s3 += Wcol[(size_t)(base + i3) << 9]; }
  }
  return (s0 + s1) + (s2 + s3);
}

__global__ __launch_bounds__(512) void reservoir_k(
    const float* __restrict__ x,    // [32,1024,8] fp32
    const float* __restrict__ Win,  // [8,512]
    const float* __restrict__ Wres, // [512,512]
    u16* __restrict__ zout)         // [32,1024,512] bf16 (0.0/1.0, exact)
{
  const int b = blockIdx.x;
  const int r = threadIdx.x;
  const int wave = r >> 6, lane = r & 63;
  __shared__ u64 s_on[2][8];
  __shared__ u64 s_off[2][8];
  __shared__ float s_x[8192];          // whole batch input, 32 KB
  __shared__ u16 s_z[16384];           // 2 x (16 steps x 512 neurons), 32 KB
  const float* xb = x + (size_t)b * 8192;
  for (int i = r; i < 8192; i += 512) s_x[i] = xb[i];
  float win[8];
#pragma unroll
  for (int i = 0; i < 8; ++i) win[i] = Win[i * 512 + r];
  const float* Wcol = Wres + r;
  u16* zb = zout + (size_t)b * 524288;
  float v = 0.f, ic = 0.f, rec = 0.f;
  int zprev = 0;
  __syncthreads();
  for (int t = 0; t < 1024; ++t) {
    if ((t & 15) == 0 && t) {
      // flush steps t-16..t-1 (other LDS buffer; 16 barriers since last write)
      const int fb = ((t >> 4) & 1) ^ 1;
      const uint4* src = (const uint4*)(s_z + fb * 8192);
      uint4* dst = (uint4*)(zb + (size_t)(t - 16) * 512);
      dst[r] = src[r];
      dst[r + 512] = src[r + 512];
    }
    const float4 xa = *(const float4*)(s_x + t * 8);
    const float4 xc = *(const float4*)(s_x + t * 8 + 4);
    // v_dec = v + 0.004*(-v + i)
    const float vdec = __fadd_rn(v, __fmul_rn(0.004f, __fadd_rn(-v, ic)));
    const float xm = __fadd_rn(vdec, -0.1f);
    const int zc = (xm > 0.f) ? 1 : 0;
    v = zc ? 0.f : vdec;
    const u64 bon = __ballot(zc && !zprev);
    const u64 boff = __ballot(!zc && zprev);
    if (lane == 0) { s_on[t & 1][wave] = bon; s_off[t & 1][wave] = boff; }
    float cur = 0.f;
    cur = fmaf(win[0], xa.x, cur);
    cur = fmaf(win[1], xa.y, cur);
    cur = fmaf(win[2], xa.z, cur);
    cur = fmaf(win[3], xa.w, cur);
    cur = fmaf(win[4], xc.x, cur);
    cur = fmaf(win[5], xc.y, cur);
    cur = fmaf(win[6], xc.z, cur);
    cur = fmaf(win[7], xc.w, cur);
    // i_new = i*0.8 + (cur + rec),  rec corresponds to z_{t-1}
    ic = __fadd_rn(__fmul_rn(ic, 0.8f), __fadd_rn(cur, rec));
    s_z[((t >> 4) & 1) * 8192 + (t & 15) * 512 + r] = zc ? (u16)0x3F80 : (u16)0;
    zprev = zc;
    __syncthreads();                       // masks + staged z visible
#pragma unroll 1
    for (int w = 0; w < 8; ++w) {
      const u64 mon = s_on[t & 1][w];
      const u64 moff = s_off[t & 1][w];
      if (mon)  rec += gather4(Wcol, mon,  w << 6);
      if (moff) rec -= gather4(Wcol, moff, w << 6);
    }
  }
  // final flush: steps 1008..1023 live in buffer 1
  {
    const uint4* src = (const uint4*)(s_z + 8192);
    uint4* dst = (uint4*)(zb + (size_t)1008 * 512);
    dst[r] = src[r];
    dst[r + 512] = src[r + 512];
  }
}

// ---------------------------------------------------------------------------
// Generic bf16 MFMA GEMM: C = epilogue(A @ B^T * scale + bias)
// A [M,K] row-major (lda), B [N,K] row-major (ldb), both bf16. fp32 bias.
// BK=32, tile BM=WM*64, BN=WN*64, 4x4 16x16x32 frags/wave.
// m97-style: async global->LDS staging (width 16), LDS stride = BK (no pad).
// ---------------------------------------------------------------------------
enum { MODE_BF16 = 0, MODE_F32 = 1, MODE_DUAL = 2, MODE_QKV = 3, MODE_AVC = 4 };

template <int WM, int WN, int MODE>
__global__ __launch_bounds__(WM * WN * 64) void gemm_bt(
    const u16* __restrict__ A, const u16* __restrict__ B,
    const float* __restrict__ bias, void* __restrict__ C0,
    void* __restrict__ C1, void* __restrict__ C2, int K, int lda, int ldb,
    int ldc, long long sA, long long sB, long long sC, int pair0, float scale,
    int relu)
{
  constexpr int BM = WM * 64, BN = WN * 64, BK = 32;
  constexpr int NT = WM * WN * 64;
  constexpr int CA = BM * 4 / NT, CB = BN * 4 / NT;  // 16B chunks per thread
  __shared__ __align__(16) u16 As[BM * BK];
  __shared__ __align__(16) u16 Bs[BN * BK];
  const int tid = threadIdx.x;
  const int bz = blockIdx.z;
  const u16* Ab = A + (size_t)bz * sA + (size_t)blockIdx.y * BM * lda;
  const u16* Bb = B + (size_t)bz * sB + (size_t)blockIdx.x * BN * ldb;
  const int wavei = tid >> 6, lane = tid & 63;
  const int r16 = lane & 15, quad = lane >> 4;
  const int wm = (wavei % WM) * 64, wn = (wavei / WM) * 64;
  floatx4 acc[4][4] = {};
  for (int k0 = 0; k0 < K; k0 += BK) {
#pragma unroll
    for (int c = 0; c < CA; ++c) {
      const int idx = c * NT + tid;
      const int row = idx >> 2, kc = (idx & 3) << 3;
      __builtin_amdgcn_global_load_lds(AS1(Ab + (size_t)row * lda + k0 + kc),
                                       AS3(As + idx * 8), 16, 0, 0);
    }
#pragma unroll
    for (int c = 0; c < CB; ++c) {
      const int idx = c * NT + tid;
      const int row = idx >> 2, kc = (idx & 3) << 3;
      __builtin_amdgcn_global_load_lds(AS1(Bb + (size_t)row * ldb + k0 + kc),
                                       AS3(Bs + idx * 8), 16, 0, 0);
    }
    __syncthreads();
    short8 af[4], bfr[4];
#pragma unroll
    for (int i = 0; i < 4; ++i)
      af[i] = *(const short8*)&As[(wm + i * 16 + r16) * BK + quad * 8];
#pragma unroll
    for (int i = 0; i < 4; ++i)
      bfr[i] = *(const short8*)&Bs[(wn + i * 16 + r16) * BK + quad * 8];
#pragma unroll
    for (int i = 0; i < 4; ++i)
#pragma unroll
      for (int j = 0; j < 4; ++j)
        acc[i][j] = __builtin_amdgcn_mfma_f32_16x16x32_bf16(af[i], bfr[j], acc[i][j], 0, 0, 0);
    __syncthreads();
  }
#pragma unroll
  for (int i = 0; i < 4; ++i) {
#pragma unroll
    for (int j = 0; j < 4; ++j) {
#pragma unroll
      for (int q = 0; q < 4; ++q) {
        const int m = blockIdx.y * BM + wm + i * 16 + quad * 4 + q;
        const int n = blockIdx.x * BN + wn + j * 16 + r16;
        float val = acc[i][j][q] * scale;
        if (bias) val += bias[n];
        if (relu) val = fmaxf(val, 0.f);
        if constexpr (MODE == MODE_BF16) {
          ((u16*)C0)[(size_t)bz * sC + (size_t)m * ldc + n] = f2bs(val);
        } else if constexpr (MODE == MODE_F32) {
          ((float*)C0)[(size_t)m * ldc + n] = val;
        } else if constexpr (MODE == MODE_DUAL) {
          ((float*)C0)[(size_t)m * ldc + n] = val;
          ((u16*)C1)[(size_t)m * ldc + n] = f2bs(val);
        } else if constexpr (MODE == MODE_QKV) {
          const int b = m >> 10, s = m & 1023;
          const u16 outv = f2bs(val);
          const int h = (n & 255) >> 6, d = n & 63;
          if (n < 256)
            ((u16*)C0)[(((size_t)(b * 4 + h)) * 1024 + s) * 64 + d] = outv;  // q [B,H,S,dh]
          else if (n < 512)
            ((u16*)C1)[(((size_t)(b * 4 + h)) * 1024 + s) * 64 + d] = outv;  // k [B,H,S,dh]
          else
            ((u16*)C2)[(((size_t)(b * 4 + h)) * 64 + d) * 1024 + s] = outv;  // v^T [B,H,dh,S]
        } else if constexpr (MODE == MODE_AVC) {
          const int p = pair0 + bz;
          const size_t coff = (size_t)(p >> 2) * 262144 + (size_t)(p & 3) * 64;
          ((u16*)C0)[coff + (size_t)m * 256 + n] = f2bs(val);  // merged [B*S, H*dh]
        }
      }
    }
  }
}

// ---------------------------------------------------------------------------
// Row softmax over 1024 bf16, in place. One wave per row (16 elems/lane).
// ---------------------------------------------------------------------------
__global__ __launch_bounds__(256) void softmax_k(u16* __restrict__ s) {
  const int row = blockIdx.x * 4 + (threadIdx.x >> 6);
  const int lane = threadIdx.x & 63;
  u16* p = s + (size_t)row * 1024 + lane * 16;
  const uint4 u0 = *(const uint4*)p;
  const uint4 u1 = *(const uint4*)(p + 8);
  float f[16] = {lo16(u0.x), hi16(u0.x), lo16(u0.y), hi16(u0.y),
                 lo16(u0.z), hi16(u0.z), lo16(u0.w), hi16(u0.w),
                 lo16(u1.x), hi16(u1.x), lo16(u1.y), hi16(u1.y),
                 lo16(u1.z), hi16(u1.z), lo16(u1.w), hi16(u1.w)};
  float mx = f[0];
#pragma unroll
  for (int i = 1; i < 16; ++i) mx = fmaxf(mx, f[i]);
#pragma unroll
  for (int off = 32; off > 0; off >>= 1) mx = fmaxf(mx, __shfl_xor(mx, off));
  float sum = 0.f;
#pragma unroll
  for (int i = 0; i < 16; ++i) { f[i] = __expf(f[i] - mx); sum += f[i]; }
#pragma unroll
  for (int off = 32; off > 0; off >>= 1) sum += __shfl_xor(sum, off);
  const float inv = 1.f / sum;
  u32 o[8];
#pragma unroll
  for (int i = 0; i < 8; ++i)
    o[i] = (u32)f2bs(f[2 * i] * inv) | ((u32)f2bs(f[2 * i + 1] * inv) << 16);
  *(uint4*)p = make_uint4(o[0], o[1], o[2], o[3]);
  *(uint4*)(p + 8) = make_uint4(o[4], o[5], o[6], o[7]);
}

// ---------------------------------------------------------------------------
// Fused residual-add + LayerNorm over 256 fp32; writes fp32 and/or bf16.
// One wave per row (4 elems/lane).
// ---------------------------------------------------------------------------
__global__ __launch_bounds__(256) void ln_k(const float* __restrict__ x,
                                            const float* __restrict__ add,
                                            const float* __restrict__ g,
                                            const float* __restrict__ bta,
                                            float* __restrict__ y32,
                                            u16* __restrict__ y16) {
  const int row = blockIdx.x * 4 + (threadIdx.x >> 6);
  const int lane = threadIdx.x & 63;
  const size_t base = (size_t)row * 256 + lane * 4;
  const float4 xv = *(const float4*)(x + base);
  const float4 av = *(const float4*)(add + base);
  float sv[4] = {xv.x + av.x, xv.y + av.y, xv.z + av.z, xv.w + av.w};
  float sum = sv[0] + sv[1] + sv[2] + sv[3];
#pragma unroll
  for (int off = 32; off > 0; off >>= 1) sum += __shfl_xor(sum, off);
  const float mean = sum * (1.f / 256.f);
  float var = 0.f;
  float d[4];
#pragma unroll
  for (int i = 0; i < 4; ++i) { d[i] = sv[i] - mean; var += d[i] * d[i]; }
#pragma unroll
  for (int off = 32; off > 0; off >>= 1) var += __shfl_xor(var, off);
  var *= (1.f / 256.f);
  const float inv = 1.f / sqrtf(var + 1e-5f);
  float yv[4];
#pragma unroll
  for (int i = 0; i < 4; ++i)
    yv[i] = d[i] * inv * g[lane * 4 + i] + bta[lane * 4 + i];
  if (y32) *(float4*)(y32 + base) = make_float4(yv[0], yv[1], yv[2], yv[3]);
  if (y16) {
    const u32 p0 = (u32)f2bs(yv[0]) | ((u32)f2bs(yv[1]) << 16);
    const u32 p1 = (u32)f2bs(yv[2]) | ((u32)f2bs(yv[3]) << 16);
    *(uint2*)(y16 + base) = make_uint2(p0, p1);
  }
}

// ---------------------------------------------------------------------------
extern "C" void kernel_launch(void* const* d_in, const int* in_sizes, int n_in,
                              void* d_out, int out_size, void* d_ws,
                              size_t ws_size, hipStream_t stream) {
  (void)in_sizes; (void)n_in; (void)out_size;
  const float* x     = (const float*)d_in[0];   // [32,1024,8]
  const float* Win   = (const float*)d_in[1];   // [8,512]
  const float* Wres  = (const float*)d_in[2];   // [512,512]
  const float* Wread = (const float*)d_in[3];   // [256,512]
  const float* bread = (const float*)d_in[4];   // [256]
  const float* Wqkv  = (const float*)d_in[5];   // [2,768,256]
  const float* bqkv  = (const float*)d_in[6];   // [2,768]
  const float* Wo    = (const float*)d_in[7];   // [2,256,256]
  const float* bo    = (const float*)d_in[8];   // [2,256]
  const float* g1    = (const float*)d_in[9];
  const float* b1    = (const float*)d_in[10];
  const float* g2    = (const float*)d_in[11];
  const float* b2    = (const float*)d_in[12];
  const float* W1    = (const float*)d_in[13];  // [2,1024,256]
  const float* c1    = (const float*)d_in[14];  // [2,1024]
  const float* W2    = (const float*)d_in[15];  // [2,256,1024]
  const float* c2    = (const float*)d_in[16];  // [2,256]

  char* ws = (char*)d_ws;
  size_t off = 0;
  auto carve = [&](size_t bytes) {
    char* p = ws + off;
    off += (bytes + 255) & ~(size_t)255;
    return p;
  };
  u16* z      = (u16*)carve((size_t)32 * 1024 * 512 * 2);    // 33.6 MB spikes (bf16)
  u16* wrd16  = (u16*)carve((size_t)256 * 512 * 2);          // bf16 weights:
  u16* wqkv16 = (u16*)carve((size_t)2 * 768 * 256 * 2);
  u16* wo16   = (u16*)carve((size_t)2 * 256 * 256 * 2);
  u16* w116   = (u16*)carve((size_t)2 * 1024 * 256 * 2);
  u16* w216   = (u16*)carve((size_t)2 * 256 * 1024 * 2);
  u16* q_s    = (u16*)carve((size_t)128 * 1024 * 64 * 2);    // [B*H,S,dh]
  u16* k_s    = (u16*)carve((size_t)128 * 1024 * 64 * 2);
  u16* v_t    = (u16*)carve((size_t)128 * 64 * 1024 * 2);    // [B*H,dh,S]
  float* h32  = (float*)carve((size_t)32768 * 256 * 4);      // residual fp32
  float* lin  = (float*)carve((size_t)32768 * 256 * 4);      // o-proj/ff2 fp32
  u16* h16    = (u16*)carve((size_t)32768 * 256 * 2);        // bf16 GEMM input
  // union region: scores chunk (CH*2MB) aliases ff1 output (64MB)
  const size_t scores128 = (size_t)128 * 1024 * 1024 * 2;    // 268.4 MB
  const size_t ff1_bytes = (size_t)32768 * 1024 * 2;         // 67.1 MB
  const int CH = (ws_size >= off + scores128) ? 128 : 32;
  u16* ff1    = (u16*)carve(CH == 128 ? scores128 : ff1_bytes);
  u16* o16    = h16;   // attention-out reuses h16 (qkv already consumed it)
  u16* scores = ff1;   // scores chunk aliases ff1

  // weight conversions (fp32 -> bf16)
  cvt_k<<<dim3(512), dim3(256), 0, stream>>>(Wread, wrd16, 131072);
  cvt_k<<<dim3(1536), dim3(256), 0, stream>>>(Wqkv, wqkv16, 393216);
  cvt_k<<<dim3(512), dim3(256), 0, stream>>>(Wo, wo16, 131072);
  cvt_k<<<dim3(2048), dim3(256), 0, stream>>>(W1, w116, 524288);
  cvt_k<<<dim3(2048), dim3(256), 0, stream>>>(W2, w216, 524288);

  reservoir_k<<<dim3(32), dim3(512), 0, stream>>>(x, Win, Wres, z);

  // readout: h = z @ Wread^T + bread  (dual fp32 + bf16)
  gemm_bt<2, 2, MODE_DUAL><<<dim3(2, 256, 1), dim3(256), 0, stream>>>(
      z, wrd16, bread, h32, h16, nullptr, 512, 512, 512, 256, 0, 0, 0, 0, 1.0f, 0);

  for (int l = 0; l < 2; ++l) {
    // qkv + scatter into q_s / k_s / v_t
    gemm_bt<2, 2, MODE_QKV><<<dim3(6, 256, 1), dim3(256), 0, stream>>>(
        h16, wqkv16 + (size_t)l * 196608, bqkv + l * 768, q_s, k_s, v_t, 256,
        256, 256, 0, 0, 0, 0, 0, 1.0f, 0);
    // attention in chunks of CH (b,h)-pairs
    for (int ch = 0; ch < 128; ch += CH) {
      gemm_bt<2, 2, MODE_BF16><<<dim3(8, 8, CH), dim3(256), 0, stream>>>(
          q_s + (size_t)ch * 65536, k_s + (size_t)ch * 65536, nullptr, scores,
          nullptr, nullptr, 64, 64, 64, 1024, 65536, 65536, 1048576, 0,
          0.125f, 0);
      softmax_k<<<dim3(256 * CH), dim3(256), 0, stream>>>(scores);
      gemm_bt<2, 1, MODE_AVC><<<dim3(1, 8, CH), dim3(128), 0, stream>>>(
          scores, v_t + (size_t)ch * 65536, nullptr, o16, nullptr, nullptr,
          1024, 1024, 1024, 0, 1048576, 65536, 0, ch, 1.0f, 0);
    }
    // o-projection -> fp32 lin
    gemm_bt<2, 2, MODE_F32><<<dim3(2, 256, 1), dim3(256), 0, stream>>>(
        o16, wo16 + (size_t)l * 65536, bo + l * 256, lin, nullptr, nullptr,
        256, 256, 256, 256, 0, 0, 0, 0, 1.0f, 0);
    // LN1(h + o)
    ln_k<<<dim3(8192), dim3(256), 0, stream>>>(h32, lin, g1 + l * 256,
                                               b1 + l * 256, h32, h16);
    // FF1 + relu
    gemm_bt<2, 2, MODE_BF16><<<dim3(8, 256, 1), dim3(256), 0, stream>>>(
        h16, w116 + (size_t)l * 262144, c1 + l * 1024, ff1, nullptr, nullptr,
        256, 256, 256, 1024, 0, 0, 0, 0, 1.0f, 1);
    // FF2 -> fp32 lin
    gemm_bt<2, 2, MODE_F32><<<dim3(2, 256, 1), dim3(256), 0, stream>>>(
        ff1, w216 + (size_t)l * 262144, c2 + l * 256, lin, nullptr, nullptr,
        1024, 1024, 1024, 256, 0, 0, 0, 0, 1.0f, 0);
    // LN2(x + ff); final layer writes fp32 straight to d_out
    float* y32 = (l == 1) ? (float*)d_out : h32;
    u16* y16 = (l == 1) ? nullptr : h16;
    ln_k<<<dim3(8192), dim3(256), 0, stream>>>(h32, lin, g2 + l * 256,
                                               b2 + l * 256, y32, y16);
  }
}

// Round 5
// 1872.708 us; speedup vs baseline: 1.2187x; 1.2187x over previous
//
#include <hip/hip_runtime.h>
#include <stdint.h>

using short8  = __attribute__((ext_vector_type(8))) short;
using floatx4 = __attribute__((ext_vector_type(4))) float;

typedef unsigned short u16;
typedef unsigned int u32;
typedef unsigned long long u64;

#define AS1(p) ((const __attribute__((address_space(1))) void*)(p))
#define AS3(p) ((__attribute__((address_space(3))) void*)(p))

__device__ __forceinline__ float bs2f(u16 u) { return __uint_as_float(((u32)u) << 16); }
__device__ __forceinline__ u16 f2bs(float f) {
  u32 x = __float_as_uint(f);
  x += 0x7FFFu + ((x >> 16) & 1u);   // RNE
  return (u16)(x >> 16);
}
__device__ __forceinline__ float lo16(u32 u) { return __uint_as_float(u << 16); }
__device__ __forceinline__ float hi16(u32 u) { return __uint_as_float(u & 0xFFFF0000u); }

// ---------------------------------------------------------------------------
// fp32 -> bf16 weight conversion (RNE)
// ---------------------------------------------------------------------------
__global__ __launch_bounds__(256) void cvt_k(const float* __restrict__ src,
                                             u16* __restrict__ dst, int n) {
  int i = blockIdx.x * 256 + threadIdx.x;
  if (i < n) dst[i] = f2bs(src[i]);
}

// ---------------------------------------------------------------------------
// LIF reservoir, single-wave design: 32 blocks (1/batch) x 64 threads.
// Each lane owns 8 neurons (lane c -> neurons 8c..8c+7). The whole 512-bit
// z state is exchanged with 8 __ballot ops per step — ZERO barriers.
// rec[r] = z @ Wres[:,r] maintained incrementally: on a toggle of neuron ro,
// the wave cooperatively reads row Wres[ro][:] (2 x dwordx4 per lane,
// coalesced 2 KB, L2-resident) and adds/subtracts into per-lane rec[8].
// State math is exact fp32 in the reference op order (proven rounds 2-4).
// ---------------------------------------------------------------------------
__global__ __launch_bounds__(64) void reservoir_k(
    const float* __restrict__ x,    // [32,1024,8] fp32
    const float* __restrict__ Win,  // [8,512]
    const float* __restrict__ Wres, // [512,512]
    u16* __restrict__ zout)         // [32,1024,512] bf16 (0.0/1.0, exact)
{
  const int b = blockIdx.x;
  const int c = threadIdx.x & 63;
  __shared__ float s_x[8200];        // batch input + 8-float pad for prefetch
  const float* xb = x + (size_t)b * 8192;
  for (int i = c * 4; i < 8192; i += 256)
    *(float4*)&s_x[i] = *(const float4*)(xb + i);
  if (c < 8) s_x[8192 + c] = 0.f;
  float win[8][8];
#pragma unroll
  for (int k = 0; k < 8; ++k)
#pragma unroll
    for (int j = 0; j < 8; ++j)
      win[j][k] = Win[k * 512 + c * 8 + j];
  u16* zb = zout + (size_t)b * 524288 + c * 8;
  float v[8] = {}, ci[8] = {}, rec[8] = {};
  u64 zprev[8] = {};
  // single wave: ds_writes above are ordered before these reads via lgkmcnt
  float4 xa = *(const float4*)&s_x[0];
  float4 xc = *(const float4*)&s_x[4];
  for (int t = 0; t < 1024; ++t) {
    const float4 na = *(const float4*)&s_x[(t + 1) * 8];      // prefetch
    const float4 nc = *(const float4*)&s_x[(t + 1) * 8 + 4];
    u64 nz[8];
    u32 zw[4];
#pragma unroll
    for (int j = 0; j < 8; ++j) {
      // v_dec = v + 0.004*(-v + i)   (i = value from previous step)
      const float vdec = __fadd_rn(v[j], __fmul_rn(0.004f, __fadd_rn(-v[j], ci[j])));
      const int zc = (__fadd_rn(vdec, -0.1f) > 0.f) ? 1 : 0;
      v[j] = zc ? 0.f : vdec;
      nz[j] = __ballot(zc);
      float cur = 0.f;
      cur = fmaf(win[j][0], xa.x, cur);
      cur = fmaf(win[j][1], xa.y, cur);
      cur = fmaf(win[j][2], xa.z, cur);
      cur = fmaf(win[j][3], xa.w, cur);
      cur = fmaf(win[j][4], xc.x, cur);
      cur = fmaf(win[j][5], xc.y, cur);
      cur = fmaf(win[j][6], xc.z, cur);
      cur = fmaf(win[j][7], xc.w, cur);
      // i_new = i*0.8 + (cur + rec),  rec corresponds to z_{t-1}
      ci[j] = __fadd_rn(__fmul_rn(ci[j], 0.8f), __fadd_rn(cur, rec[j]));
      if (j & 1) zw[j >> 1] |= zc ? 0x3F800000u : 0u;
      else       zw[j >> 1]  = zc ? 0x3F80u : 0u;
    }
    *(uint4*)(zb + (size_t)t * 512) = make_uint4(zw[0], zw[1], zw[2], zw[3]);
    // toggle processing: update rec to reflect z_t (used at t+1)
#pragma unroll
    for (int j = 0; j < 8; ++j) {
      u64 on  = nz[j] & ~zprev[j];
      u64 offm = zprev[j] & ~nz[j];
      zprev[j] = nz[j];
      while (on) {
        const int cc = __builtin_ctzll(on); on &= on - 1;
        const float* wr = Wres + ((size_t)(cc * 8 + j) << 9) + c * 8;
        const float4 w0 = *(const float4*)wr;
        const float4 w1 = *(const float4*)(wr + 4);
        rec[0] += w0.x; rec[1] += w0.y; rec[2] += w0.z; rec[3] += w0.w;
        rec[4] += w1.x; rec[5] += w1.y; rec[6] += w1.z; rec[7] += w1.w;
      }
      while (offm) {
        const int cc = __builtin_ctzll(offm); offm &= offm - 1;
        const float* wr = Wres + ((size_t)(cc * 8 + j) << 9) + c * 8;
        const float4 w0 = *(const float4*)wr;
        const float4 w1 = *(const float4*)(wr + 4);
        rec[0] -= w0.x; rec[1] -= w0.y; rec[2] -= w0.z; rec[3] -= w0.w;
        rec[4] -= w1.x; rec[5] -= w1.y; rec[6] -= w1.z; rec[7] -= w1.w;
      }
    }
    xa = na; xc = nc;
  }
}

// ---------------------------------------------------------------------------
// Generic bf16 MFMA GEMM: C = epilogue(A @ B^T * scale + bias)
// A [M,K] row-major (lda), B [N,K] row-major (ldb), both bf16. fp32 bias.
// BK=32, tile BM=WM*64, BN=WN*64, 4x4 16x16x32 frags/wave.
// m97-style: async global->LDS staging (width 16), LDS stride = BK (no pad).
// ---------------------------------------------------------------------------
enum { MODE_BF16 = 0, MODE_F32 = 1, MODE_DUAL = 2, MODE_QKV = 3, MODE_AVC = 4 };

template <int WM, int WN, int MODE>
__global__ __launch_bounds__(WM * WN * 64) void gemm_bt(
    const u16* __restrict__ A, const u16* __restrict__ B,
    const float* __restrict__ bias, void* __restrict__ C0,
    void* __restrict__ C1, void* __restrict__ C2, int K, int lda, int ldb,
    int ldc, long long sA, long long sB, long long sC, int pair0, float scale,
    int relu)
{
  constexpr int BM = WM * 64, BN = WN * 64, BK = 32;
  constexpr int NT = WM * WN * 64;
  constexpr int CA = BM * 4 / NT, CB = BN * 4 / NT;  // 16B chunks per thread
  __shared__ __align__(16) u16 As[BM * BK];
  __shared__ __align__(16) u16 Bs[BN * BK];
  const int tid = threadIdx.x;
  const int bz = blockIdx.z;
  const u16* Ab = A + (size_t)bz * sA + (size_t)blockIdx.y * BM * lda;
  const u16* Bb = B + (size_t)bz * sB + (size_t)blockIdx.x * BN * ldb;
  const int wavei = tid >> 6, lane = tid & 63;
  const int r16 = lane & 15, quad = lane >> 4;
  const int wm = (wavei % WM) * 64, wn = (wavei / WM) * 64;
  floatx4 acc[4][4] = {};
  for (int k0 = 0; k0 < K; k0 += BK) {
#pragma unroll
    for (int c = 0; c < CA; ++c) {
      const int idx = c * NT + tid;
      const int row = idx >> 2, kc = (idx & 3) << 3;
      __builtin_amdgcn_global_load_lds(AS1(Ab + (size_t)row * lda + k0 + kc),
                                       AS3(As + idx * 8), 16, 0, 0);
    }
#pragma unroll
    for (int c = 0; c < CB; ++c) {
      const int idx = c * NT + tid;
      const int row = idx >> 2, kc = (idx & 3) << 3;
      __builtin_amdgcn_global_load_lds(AS1(Bb + (size_t)row * ldb + k0 + kc),
                                       AS3(Bs + idx * 8), 16, 0, 0);
    }
    __syncthreads();
    short8 af[4], bfr[4];
#pragma unroll
    for (int i = 0; i < 4; ++i)
      af[i] = *(const short8*)&As[(wm + i * 16 + r16) * BK + quad * 8];
#pragma unroll
    for (int i = 0; i < 4; ++i)
      bfr[i] = *(const short8*)&Bs[(wn + i * 16 + r16) * BK + quad * 8];
#pragma unroll
    for (int i = 0; i < 4; ++i)
#pragma unroll
      for (int j = 0; j < 4; ++j)
        acc[i][j] = __builtin_amdgcn_mfma_f32_16x16x32_bf16(af[i], bfr[j], acc[i][j], 0, 0, 0);
    __syncthreads();
  }
#pragma unroll
  for (int i = 0; i < 4; ++i) {
#pragma unroll
    for (int j = 0; j < 4; ++j) {
#pragma unroll
      for (int q = 0; q < 4; ++q) {
        const int m = blockIdx.y * BM + wm + i * 16 + quad * 4 + q;
        const int n = blockIdx.x * BN + wn + j * 16 + r16;
        float val = acc[i][j][q] * scale;
        if (bias) val += bias[n];
        if (relu) val = fmaxf(val, 0.f);
        if constexpr (MODE == MODE_BF16) {
          ((u16*)C0)[(size_t)bz * sC + (size_t)m * ldc + n] = f2bs(val);
        } else if constexpr (MODE == MODE_F32) {
          ((float*)C0)[(size_t)m * ldc + n] = val;
        } else if constexpr (MODE == MODE_DUAL) {
          ((float*)C0)[(size_t)m * ldc + n] = val;
          ((u16*)C1)[(size_t)m * ldc + n] = f2bs(val);
        } else if constexpr (MODE == MODE_QKV) {
          const int b = m >> 10, s = m & 1023;
          const u16 outv = f2bs(val);
          const int h = (n & 255) >> 6, d = n & 63;
          if (n < 256)
            ((u16*)C0)[(((size_t)(b * 4 + h)) * 1024 + s) * 64 + d] = outv;  // q [B,H,S,dh]
          else if (n < 512)
            ((u16*)C1)[(((size_t)(b * 4 + h)) * 1024 + s) * 64 + d] = outv;  // k [B,H,S,dh]
          else
            ((u16*)C2)[(((size_t)(b * 4 + h)) * 64 + d) * 1024 + s] = outv;  // v^T [B,H,dh,S]
        } else if constexpr (MODE == MODE_AVC) {
          const int p = pair0 + bz;
          const size_t coff = (size_t)(p >> 2) * 262144 + (size_t)(p & 3) * 64;
          ((u16*)C0)[coff + (size_t)m * 256 + n] = f2bs(val);  // merged [B*S, H*dh]
        }
      }
    }
  }
}

// ---------------------------------------------------------------------------
// Row softmax over 1024 bf16, in place. One wave per row (16 elems/lane).
// ---------------------------------------------------------------------------
__global__ __launch_bounds__(256) void softmax_k(u16* __restrict__ s) {
  const int row = blockIdx.x * 4 + (threadIdx.x >> 6);
  const int lane = threadIdx.x & 63;
  u16* p = s + (size_t)row * 1024 + lane * 16;
  const uint4 u0 = *(const uint4*)p;
  const uint4 u1 = *(const uint4*)(p + 8);
  float f[16] = {lo16(u0.x), hi16(u0.x), lo16(u0.y), hi16(u0.y),
                 lo16(u0.z), hi16(u0.z), lo16(u0.w), hi16(u0.w),
                 lo16(u1.x), hi16(u1.x), lo16(u1.y), hi16(u1.y),
                 lo16(u1.z), hi16(u1.z), lo16(u1.w), hi16(u1.w)};
  float mx = f[0];
#pragma unroll
  for (int i = 1; i < 16; ++i) mx = fmaxf(mx, f[i]);
#pragma unroll
  for (int off = 32; off > 0; off >>= 1) mx = fmaxf(mx, __shfl_xor(mx, off));
  float sum = 0.f;
#pragma unroll
  for (int i = 0; i < 16; ++i) { f[i] = __expf(f[i] - mx); sum += f[i]; }
#pragma unroll
  for (int off = 32; off > 0; off >>= 1) sum += __shfl_xor(sum, off);
  const float inv = 1.f / sum;
  u32 o[8];
#pragma unroll
  for (int i = 0; i < 8; ++i)
    o[i] = (u32)f2bs(f[2 * i] * inv) | ((u32)f2bs(f[2 * i + 1] * inv) << 16);
  *(uint4*)p = make_uint4(o[0], o[1], o[2], o[3]);
  *(uint4*)(p + 8) = make_uint4(o[4], o[5], o[6], o[7]);
}

// ---------------------------------------------------------------------------
// Fused residual-add + LayerNorm over 256 fp32; writes fp32 and/or bf16.
// One wave per row (4 elems/lane).
// ---------------------------------------------------------------------------
__global__ __launch_bounds__(256) void ln_k(const float* __restrict__ x,
                                            const float* __restrict__ add,
                                            const float* __restrict__ g,
                                            const float* __restrict__ bta,
                                            float* __restrict__ y32,
                                            u16* __restrict__ y16) {
  const int row = blockIdx.x * 4 + (threadIdx.x >> 6);
  const int lane = threadIdx.x & 63;
  const size_t base = (size_t)row * 256 + lane * 4;
  const float4 xv = *(const float4*)(x + base);
  const float4 av = *(const float4*)(add + base);
  float sv[4] = {xv.x + av.x, xv.y + av.y, xv.z + av.z, xv.w + av.w};
  float sum = sv[0] + sv[1] + sv[2] + sv[3];
#pragma unroll
  for (int off = 32; off > 0; off >>= 1) sum += __shfl_xor(sum, off);
  const float mean = sum * (1.f / 256.f);
  float var = 0.f;
  float d[4];
#pragma unroll
  for (int i = 0; i < 4; ++i) { d[i] = sv[i] - mean; var += d[i] * d[i]; }
#pragma unroll
  for (int off = 32; off > 0; off >>= 1) var += __shfl_xor(var, off);
  var *= (1.f / 256.f);
  const float inv = 1.f / sqrtf(var + 1e-5f);
  float yv[4];
#pragma unroll
  for (int i = 0; i < 4; ++i)
    yv[i] = d[i] * inv * g[lane * 4 + i] + bta[lane * 4 + i];
  if (y32) *(float4*)(y32 + base) = make_float4(yv[0], yv[1], yv[2], yv[3]);
  if (y16) {
    const u32 p0 = (u32)f2bs(yv[0]) | ((u32)f2bs(yv[1]) << 16);
    const u32 p1 = (u32)f2bs(yv[2]) | ((u32)f2bs(yv[3]) << 16);
    *(uint2*)(y16 + base) = make_uint2(p0, p1);
  }
}

// ---------------------------------------------------------------------------
extern "C" void kernel_launch(void* const* d_in, const int* in_sizes, int n_in,
                              void* d_out, int out_size, void* d_ws,
                              size_t ws_size, hipStream_t stream) {
  (void)in_sizes; (void)n_in; (void)out_size;
  const float* x     = (const float*)d_in[0];   // [32,1024,8]
  const float* Win   = (const float*)d_in[1];   // [8,512]
  const float* Wres  = (const float*)d_in[2];   // [512,512]
  const float* Wread = (const float*)d_in[3];   // [256,512]
  const float* bread = (const float*)d_in[4];   // [256]
  const float* Wqkv  = (const float*)d_in[5];   // [2,768,256]
  const float* bqkv  = (const float*)d_in[6];   // [2,768]
  const float* Wo    = (const float*)d_in[7];   // [2,256,256]
  const float* bo    = (const float*)d_in[8];   // [2,256]
  const float* g1    = (const float*)d_in[9];
  const float* b1    = (const float*)d_in[10];
  const float* g2    = (const float*)d_in[11];
  const float* b2    = (const float*)d_in[12];
  const float* W1    = (const float*)d_in[13];  // [2,1024,256]
  const float* c1    = (const float*)d_in[14];  // [2,1024]
  const float* W2    = (const float*)d_in[15];  // [2,256,1024]
  const float* c2    = (const float*)d_in[16];  // [2,256]

  char* ws = (char*)d_ws;
  size_t off = 0;
  auto carve = [&](size_t bytes) {
    char* p = ws + off;
    off += (bytes + 255) & ~(size_t)255;
    return p;
  };
  u16* z      = (u16*)carve((size_t)32 * 1024 * 512 * 2);    // 33.6 MB spikes (bf16)
  u16* wrd16  = (u16*)carve((size_t)256 * 512 * 2);          // bf16 weights:
  u16* wqkv16 = (u16*)carve((size_t)2 * 768 * 256 * 2);
  u16* wo16   = (u16*)carve((size_t)2 * 256 * 256 * 2);
  u16* w116   = (u16*)carve((size_t)2 * 1024 * 256 * 2);
  u16* w216   = (u16*)carve((size_t)2 * 256 * 1024 * 2);
  u16* q_s    = (u16*)carve((size_t)128 * 1024 * 64 * 2);    // [B*H,S,dh]
  u16* k_s    = (u16*)carve((size_t)128 * 1024 * 64 * 2);
  u16* v_t    = (u16*)carve((size_t)128 * 64 * 1024 * 2);    // [B*H,dh,S]
  float* h32  = (float*)carve((size_t)32768 * 256 * 4);      // residual fp32
  float* lin  = (float*)carve((size_t)32768 * 256 * 4);      // o-proj/ff2 fp32
  u16* h16    = (u16*)carve((size_t)32768 * 256 * 2);        // bf16 GEMM input
  // union region: scores chunk (CH*2MB) aliases ff1 output (64MB)
  const size_t scores128 = (size_t)128 * 1024 * 1024 * 2;    // 268.4 MB
  const size_t ff1_bytes = (size_t)32768 * 1024 * 2;         // 67.1 MB
  const int CH = (ws_size >= off + scores128) ? 128 : 32;
  u16* ff1    = (u16*)carve(CH == 128 ? scores128 : ff1_bytes);
  u16* o16    = h16;   // attention-out reuses h16 (qkv already consumed it)
  u16* scores = ff1;   // scores chunk aliases ff1

  // weight conversions (fp32 -> bf16)
  cvt_k<<<dim3(512), dim3(256), 0, stream>>>(Wread, wrd16, 131072);
  cvt_k<<<dim3(1536), dim3(256), 0, stream>>>(Wqkv, wqkv16, 393216);
  cvt_k<<<dim3(512), dim3(256), 0, stream>>>(Wo, wo16, 131072);
  cvt_k<<<dim3(2048), dim3(256), 0, stream>>>(W1, w116, 524288);
  cvt_k<<<dim3(2048), dim3(256), 0, stream>>>(W2, w216, 524288);

  reservoir_k<<<dim3(32), dim3(64), 0, stream>>>(x, Win, Wres, z);

  // readout: h = z @ Wread^T + bread  (dual fp32 + bf16)
  gemm_bt<2, 2, MODE_DUAL><<<dim3(2, 256, 1), dim3(256), 0, stream>>>(
      z, wrd16, bread, h32, h16, nullptr, 512, 512, 512, 256, 0, 0, 0, 0, 1.0f, 0);

  for (int l = 0; l < 2; ++l) {
    // qkv + scatter into q_s / k_s / v_t
    gemm_bt<2, 2, MODE_QKV><<<dim3(6, 256, 1), dim3(256), 0, stream>>>(
        h16, wqkv16 + (size_t)l * 196608, bqkv + l * 768, q_s, k_s, v_t, 256,
        256, 256, 0, 0, 0, 0, 0, 1.0f, 0);
    // attention in chunks of CH (b,h)-pairs
    for (int ch = 0; ch < 128; ch += CH) {
      gemm_bt<2, 2, MODE_BF16><<<dim3(8, 8, CH), dim3(256), 0, stream>>>(
          q_s + (size_t)ch * 65536, k_s + (size_t)ch * 65536, nullptr, scores,
          nullptr, nullptr, 64, 64, 64, 1024, 65536, 65536, 1048576, 0,
          0.125f, 0);
      softmax_k<<<dim3(256 * CH), dim3(256), 0, stream>>>(scores);
      gemm_bt<2, 1, MODE_AVC><<<dim3(1, 8, CH), dim3(128), 0, stream>>>(
          scores, v_t + (size_t)ch * 65536, nullptr, o16, nullptr, nullptr,
          1024, 1024, 1024, 0, 1048576, 65536, 0, ch, 1.0f, 0);
    }
    // o-projection -> fp32 lin
    gemm_bt<2, 2, MODE_F32><<<dim3(2, 256, 1), dim3(256), 0, stream>>>(
        o16, wo16 + (size_t)l * 65536, bo + l * 256, lin, nullptr, nullptr,
        256, 256, 256, 256, 0, 0, 0, 0, 1.0f, 0);
    // LN1(h + o)
    ln_k<<<dim3(8192), dim3(256), 0, stream>>>(h32, lin, g1 + l * 256,
                                               b1 + l * 256, h32, h16);
    // FF1 + relu
    gemm_bt<2, 2, MODE_BF16><<<dim3(8, 256, 1), dim3(256), 0, stream>>>(
        h16, w116 + (size_t)l * 262144, c1 + l * 1024, ff1, nullptr, nullptr,
        256, 256, 256, 1024, 0, 0, 0, 0, 1.0f, 1);
    // FF2 -> fp32 lin
    gemm_bt<2, 2, MODE_F32><<<dim3(2, 256, 1), dim3(256), 0, stream>>>(
        ff1, w216 + (size_t)l * 262144, c2 + l * 256, lin, nullptr, nullptr,
        1024, 1024, 1024, 256, 0, 0, 0, 0, 1.0f, 0);
    // LN2(x + ff); final layer writes fp32 straight to d_out
    float* y32 = (l == 1) ? (float*)d_out : h32;
    u16* y16 = (l == 1) ? nullptr : h16;
    ln_k<<<dim3(8192), dim3(256), 0, stream>>>(h32, lin, g2 + l * 256,
                                               b2 + l * 256, y32, y16);
  }
}

// Round 6
// 1674.315 us; speedup vs baseline: 1.3631x; 1.1185x over previous
//
#include <hip/hip_runtime.h>
#include <stdint.h>

using short8  = __attribute__((ext_vector_type(8))) short;
using floatx4 = __attribute__((ext_vector_type(4))) float;

typedef unsigned short u16;
typedef unsigned int u32;
typedef unsigned long long u64;

#define AS1(p) ((const __attribute__((address_space(1))) void*)(p))
#define AS3(p) ((__attribute__((address_space(3))) void*)(p))

__device__ __forceinline__ float bs2f(u16 u) { return __uint_as_float(((u32)u) << 16); }
__device__ __forceinline__ u16 f2bs(float f) {
  u32 x = __float_as_uint(f);
  x += 0x7FFFu + ((x >> 16) & 1u);   // RNE
  return (u16)(x >> 16);
}
__device__ __forceinline__ float lo16(u32 u) { return __uint_as_float(u << 16); }
__device__ __forceinline__ float hi16(u32 u) { return __uint_as_float(u & 0xFFFF0000u); }

// ---------------------------------------------------------------------------
// fp32 -> bf16 weight conversion (RNE)
// ---------------------------------------------------------------------------
__global__ __launch_bounds__(256) void cvt_k(const float* __restrict__ src,
                                             u16* __restrict__ dst, int n) {
  int i = blockIdx.x * 256 + threadIdx.x;
  if (i < n) dst[i] = f2bs(src[i]);
}

// ---------------------------------------------------------------------------
// LIF reservoir, single-wave: 32 blocks (1/batch) x 64 threads, lane c owns
// neurons 8c..8c+7. z exchanged with 8 ballots/step — no barriers at all.
// t-loop unrolled x8: per-step z-store WAR waits vanish (renamed reg sets,
// store retires 8 steps before reuse) and x ds_reads are hoisted/batched.
// Steady-state toggle check is ONE uniform scalar branch per step.
// State math exact fp32 in reference op order (bitwise-stable rounds 2-5).
// ---------------------------------------------------------------------------
__global__ __launch_bounds__(64) void reservoir_k(
    const float* __restrict__ x,    // [32,1024,8] fp32
    const float* __restrict__ Win,  // [8,512]
    const float* __restrict__ Wres, // [512,512]
    u16* __restrict__ zout)         // [32,1024,512] bf16 (0.0/1.0, exact)
{
  const int b = blockIdx.x;
  const int c = threadIdx.x & 63;
  __shared__ float s_x[8192];
  const float* xb = x + (size_t)b * 8192;
  for (int i = c * 4; i < 8192; i += 256)
    *(float4*)&s_x[i] = *(const float4*)(xb + i);
  float win[8][8];
#pragma unroll
  for (int k = 0; k < 8; ++k)
#pragma unroll
    for (int j = 0; j < 8; ++j)
      win[j][k] = Win[k * 512 + c * 8 + j];
  u16* zb = zout + (size_t)b * 524288 + c * 8;
  float v[8] = {}, ci[8] = {}, rec[8] = {};
  u64 zprev[8] = {};
  for (int tb = 0; tb < 128; ++tb) {
#pragma unroll
    for (int u = 0; u < 8; ++u) {
      const int t = tb * 8 + u;
      const float4 xa = *(const float4*)&s_x[t * 8];
      const float4 xc = *(const float4*)&s_x[t * 8 + 4];
      u64 nz[8];
      u32 zw[4];
#pragma unroll
      for (int j = 0; j < 8; ++j) {
        // v_dec = v + 0.004*(-v + i)   (i = value from previous step)
        const float vdec = __fadd_rn(v[j], __fmul_rn(0.004f, __fadd_rn(-v[j], ci[j])));
        const int zc = (__fadd_rn(vdec, -0.1f) > 0.f) ? 1 : 0;
        v[j] = zc ? 0.f : vdec;
        nz[j] = __ballot(zc);
        float cur = 0.f;
        cur = fmaf(win[j][0], xa.x, cur);
        cur = fmaf(win[j][1], xa.y, cur);
        cur = fmaf(win[j][2], xa.z, cur);
        cur = fmaf(win[j][3], xa.w, cur);
        cur = fmaf(win[j][4], xc.x, cur);
        cur = fmaf(win[j][5], xc.y, cur);
        cur = fmaf(win[j][6], xc.z, cur);
        cur = fmaf(win[j][7], xc.w, cur);
        // i_new = i*0.8 + (cur + rec),  rec corresponds to z_{t-1}
        ci[j] = __fadd_rn(__fmul_rn(ci[j], 0.8f), __fadd_rn(cur, rec[j]));
        if (j & 1) zw[j >> 1] |= zc ? 0x3F800000u : 0u;
        else       zw[j >> 1]  = zc ? 0x3F80u : 0u;
      }
      *(uint4*)(zb + (size_t)t * 512) = make_uint4(zw[0], zw[1], zw[2], zw[3]);
      u64 anyt = 0;
#pragma unroll
      for (int j = 0; j < 8; ++j) anyt |= nz[j] ^ zprev[j];
      if (anyt) {                    // uniform scalar branch; rare after ignition
#pragma unroll
        for (int j = 0; j < 8; ++j) {
          u64 on   = nz[j] & ~zprev[j];
          u64 offm = zprev[j] & ~nz[j];
          while (on) {
            const int cc = __builtin_ctzll(on); on &= on - 1;
            const float* wr = Wres + ((size_t)(cc * 8 + j) << 9) + c * 8;
            const float4 w0 = *(const float4*)wr;
            const float4 w1 = *(const float4*)(wr + 4);
            rec[0] += w0.x; rec[1] += w0.y; rec[2] += w0.z; rec[3] += w0.w;
            rec[4] += w1.x; rec[5] += w1.y; rec[6] += w1.z; rec[7] += w1.w;
          }
          while (offm) {
            const int cc = __builtin_ctzll(offm); offm &= offm - 1;
            const float* wr = Wres + ((size_t)(cc * 8 + j) << 9) + c * 8;
            const float4 w0 = *(const float4*)wr;
            const float4 w1 = *(const float4*)(wr + 4);
            rec[0] -= w0.x; rec[1] -= w0.y; rec[2] -= w0.z; rec[3] -= w0.w;
            rec[4] -= w1.x; rec[5] -= w1.y; rec[6] -= w1.z; rec[7] -= w1.w;
          }
        }
      }
#pragma unroll
      for (int j = 0; j < 8; ++j) zprev[j] = nz[j];
    }
  }
}

// ---------------------------------------------------------------------------
// Generic bf16 MFMA GEMM: C = epilogue(A @ B^T * scale + bias)
// A [M,K] row-major (lda), B [N,K] row-major (ldb), both bf16. fp32 bias.
// BK=32, tile BM=WM*64, BN=WN*64, 4x4 16x16x32 frags/wave.
// m97-style: async global->LDS staging (width 16), LDS stride = BK (no pad).
// ---------------------------------------------------------------------------
enum { MODE_BF16 = 0, MODE_F32 = 1, MODE_DUAL = 2, MODE_QKV = 3, MODE_AVC = 4 };

template <int WM, int WN, int MODE>
__global__ __launch_bounds__(WM * WN * 64) void gemm_bt(
    const u16* __restrict__ A, const u16* __restrict__ B,
    const float* __restrict__ bias, void* __restrict__ C0,
    void* __restrict__ C1, void* __restrict__ C2, int K, int lda, int ldb,
    int ldc, long long sA, long long sB, long long sC, int pair0, float scale,
    int relu)
{
  constexpr int BM = WM * 64, BN = WN * 64, BK = 32;
  constexpr int NT = WM * WN * 64;
  constexpr int CA = BM * 4 / NT, CB = BN * 4 / NT;  // 16B chunks per thread
  __shared__ __align__(16) u16 As[BM * BK];
  __shared__ __align__(16) u16 Bs[BN * BK];
  const int tid = threadIdx.x;
  const int bz = blockIdx.z;
  const u16* Ab = A + (size_t)bz * sA + (size_t)blockIdx.y * BM * lda;
  const u16* Bb = B + (size_t)bz * sB + (size_t)blockIdx.x * BN * ldb;
  const int wavei = tid >> 6, lane = tid & 63;
  const int r16 = lane & 15, quad = lane >> 4;
  const int wm = (wavei % WM) * 64, wn = (wavei / WM) * 64;
  floatx4 acc[4][4] = {};
  for (int k0 = 0; k0 < K; k0 += BK) {
#pragma unroll
    for (int c = 0; c < CA; ++c) {
      const int idx = c * NT + tid;
      const int row = idx >> 2, kc = (idx & 3) << 3;
      __builtin_amdgcn_global_load_lds(AS1(Ab + (size_t)row * lda + k0 + kc),
                                       AS3(As + idx * 8), 16, 0, 0);
    }
#pragma unroll
    for (int c = 0; c < CB; ++c) {
      const int idx = c * NT + tid;
      const int row = idx >> 2, kc = (idx & 3) << 3;
      __builtin_amdgcn_global_load_lds(AS1(Bb + (size_t)row * ldb + k0 + kc),
                                       AS3(Bs + idx * 8), 16, 0, 0);
    }
    __syncthreads();
    short8 af[4], bfr[4];
#pragma unroll
    for (int i = 0; i < 4; ++i)
      af[i] = *(const short8*)&As[(wm + i * 16 + r16) * BK + quad * 8];
#pragma unroll
    for (int i = 0; i < 4; ++i)
      bfr[i] = *(const short8*)&Bs[(wn + i * 16 + r16) * BK + quad * 8];
#pragma unroll
    for (int i = 0; i < 4; ++i)
#pragma unroll
      for (int j = 0; j < 4; ++j)
        acc[i][j] = __builtin_amdgcn_mfma_f32_16x16x32_bf16(af[i], bfr[j], acc[i][j], 0, 0, 0);
    __syncthreads();
  }
#pragma unroll
  for (int i = 0; i < 4; ++i) {
#pragma unroll
    for (int j = 0; j < 4; ++j) {
#pragma unroll
      for (int q = 0; q < 4; ++q) {
        const int m = blockIdx.y * BM + wm + i * 16 + quad * 4 + q;
        const int n = blockIdx.x * BN + wn + j * 16 + r16;
        float val = acc[i][j][q] * scale;
        if (bias) val += bias[n];
        if (relu) val = fmaxf(val, 0.f);
        if constexpr (MODE == MODE_BF16) {
          ((u16*)C0)[(size_t)bz * sC + (size_t)m * ldc + n] = f2bs(val);
        } else if constexpr (MODE == MODE_F32) {
          ((float*)C0)[(size_t)m * ldc + n] = val;
        } else if constexpr (MODE == MODE_DUAL) {
          ((float*)C0)[(size_t)m * ldc + n] = val;
          ((u16*)C1)[(size_t)m * ldc + n] = f2bs(val);
        } else if constexpr (MODE == MODE_QKV) {
          const int b = m >> 10, s = m & 1023;
          const u16 outv = f2bs(val);
          const int h = (n & 255) >> 6, d = n & 63;
          if (n < 256)
            ((u16*)C0)[(((size_t)(b * 4 + h)) * 1024 + s) * 64 + d] = outv;  // q [B,H,S,dh]
          else if (n < 512)
            ((u16*)C1)[(((size_t)(b * 4 + h)) * 1024 + s) * 64 + d] = outv;  // k [B,H,S,dh]
          else
            ((u16*)C2)[(((size_t)(b * 4 + h)) * 64 + d) * 1024 + s] = outv;  // v^T [B,H,dh,S]
        } else if constexpr (MODE == MODE_AVC) {
          const int p = pair0 + bz;
          const size_t coff = (size_t)(p >> 2) * 262144 + (size_t)(p & 3) * 64;
          ((u16*)C0)[coff + (size_t)m * 256 + n] = f2bs(val);  // merged [B*S, H*dh]
        }
      }
    }
  }
}

// ---------------------------------------------------------------------------
// Row softmax over 1024 bf16, in place. One wave per row (16 elems/lane).
// ---------------------------------------------------------------------------
__global__ __launch_bounds__(256) void softmax_k(u16* __restrict__ s) {
  const int row = blockIdx.x * 4 + (threadIdx.x >> 6);
  const int lane = threadIdx.x & 63;
  u16* p = s + (size_t)row * 1024 + lane * 16;
  const uint4 u0 = *(const uint4*)p;
  const uint4 u1 = *(const uint4*)(p + 8);
  float f[16] = {lo16(u0.x), hi16(u0.x), lo16(u0.y), hi16(u0.y),
                 lo16(u0.z), hi16(u0.z), lo16(u0.w), hi16(u0.w),
                 lo16(u1.x), hi16(u1.x), lo16(u1.y), hi16(u1.y),
                 lo16(u1.z), hi16(u1.z), lo16(u1.w), hi16(u1.w)};
  float mx = f[0];
#pragma unroll
  for (int i = 1; i < 16; ++i) mx = fmaxf(mx, f[i]);
#pragma unroll
  for (int off = 32; off > 0; off >>= 1) mx = fmaxf(mx, __shfl_xor(mx, off));
  float sum = 0.f;
#pragma unroll
  for (int i = 0; i < 16; ++i) { f[i] = __expf(f[i] - mx); sum += f[i]; }
#pragma unroll
  for (int off = 32; off > 0; off >>= 1) sum += __shfl_xor(sum, off);
  const float inv = 1.f / sum;
  u32 o[8];
#pragma unroll
  for (int i = 0; i < 8; ++i)
    o[i] = (u32)f2bs(f[2 * i] * inv) | ((u32)f2bs(f[2 * i + 1] * inv) << 16);
  *(uint4*)p = make_uint4(o[0], o[1], o[2], o[3]);
  *(uint4*)(p + 8) = make_uint4(o[4], o[5], o[6], o[7]);
}

// ---------------------------------------------------------------------------
// Fused residual-add + LayerNorm over 256 fp32; writes fp32 and/or bf16.
// One wave per row (4 elems/lane).
// ---------------------------------------------------------------------------
__global__ __launch_bounds__(256) void ln_k(const float* __restrict__ x,
                                            const float* __restrict__ add,
                                            const float* __restrict__ g,
                                            const float* __restrict__ bta,
                                            float* __restrict__ y32,
                                            u16* __restrict__ y16) {
  const int row = blockIdx.x * 4 + (threadIdx.x >> 6);
  const int lane = threadIdx.x & 63;
  const size_t base = (size_t)row * 256 + lane * 4;
  const float4 xv = *(const float4*)(x + base);
  const float4 av = *(const float4*)(add + base);
  float sv[4] = {xv.x + av.x, xv.y + av.y, xv.z + av.z, xv.w + av.w};
  float sum = sv[0] + sv[1] + sv[2] + sv[3];
#pragma unroll
  for (int off = 32; off > 0; off >>= 1) sum += __shfl_xor(sum, off);
  const float mean = sum * (1.f / 256.f);
  float var = 0.f;
  float d[4];
#pragma unroll
  for (int i = 0; i < 4; ++i) { d[i] = sv[i] - mean; var += d[i] * d[i]; }
#pragma unroll
  for (int off = 32; off > 0; off >>= 1) var += __shfl_xor(var, off);
  var *= (1.f / 256.f);
  const float inv = 1.f / sqrtf(var + 1e-5f);
  float yv[4];
#pragma unroll
  for (int i = 0; i < 4; ++i)
    yv[i] = d[i] * inv * g[lane * 4 + i] + bta[lane * 4 + i];
  if (y32) *(float4*)(y32 + base) = make_float4(yv[0], yv[1], yv[2], yv[3]);
  if (y16) {
    const u32 p0 = (u32)f2bs(yv[0]) | ((u32)f2bs(yv[1]) << 16);
    const u32 p1 = (u32)f2bs(yv[2]) | ((u32)f2bs(yv[3]) << 16);
    *(uint2*)(y16 + base) = make_uint2(p0, p1);
  }
}

// ---------------------------------------------------------------------------
extern "C" void kernel_launch(void* const* d_in, const int* in_sizes, int n_in,
                              void* d_out, int out_size, void* d_ws,
                              size_t ws_size, hipStream_t stream) {
  (void)in_sizes; (void)n_in; (void)out_size; (void)ws_size;
  const float* x     = (const float*)d_in[0];   // [32,1024,8]
  const float* Win   = (const float*)d_in[1];   // [8,512]
  const float* Wres  = (const float*)d_in[2];   // [512,512]
  const float* Wread = (const float*)d_in[3];   // [256,512]
  const float* bread = (const float*)d_in[4];   // [256]
  const float* Wqkv  = (const float*)d_in[5];   // [2,768,256]
  const float* bqkv  = (const float*)d_in[6];   // [2,768]
  const float* Wo    = (const float*)d_in[7];   // [2,256,256]
  const float* bo    = (const float*)d_in[8];   // [2,256]
  const float* g1    = (const float*)d_in[9];
  const float* b1    = (const float*)d_in[10];
  const float* g2    = (const float*)d_in[11];
  const float* b2    = (const float*)d_in[12];
  const float* W1    = (const float*)d_in[13];  // [2,1024,256]
  const float* c1    = (const float*)d_in[14];  // [2,1024]
  const float* W2    = (const float*)d_in[15];  // [2,256,1024]
  const float* c2    = (const float*)d_in[16];  // [2,256]

  char* ws = (char*)d_ws;
  size_t off = 0;
  auto carve = [&](size_t bytes) {
    char* p = ws + off;
    off += (bytes + 255) & ~(size_t)255;
    return p;
  };
  u16* z      = (u16*)carve((size_t)32 * 1024 * 512 * 2);    // 33.6 MB spikes (bf16)
  u16* wrd16  = (u16*)carve((size_t)256 * 512 * 2);          // bf16 weights:
  u16* wqkv16 = (u16*)carve((size_t)2 * 768 * 256 * 2);
  u16* wo16   = (u16*)carve((size_t)2 * 256 * 256 * 2);
  u16* w116   = (u16*)carve((size_t)2 * 1024 * 256 * 2);
  u16* w216   = (u16*)carve((size_t)2 * 256 * 1024 * 2);
  u16* q_s    = (u16*)carve((size_t)128 * 1024 * 64 * 2);    // [B*H,S,dh]
  u16* k_s    = (u16*)carve((size_t)128 * 1024 * 64 * 2);
  u16* v_t    = (u16*)carve((size_t)128 * 64 * 1024 * 2);    // [B*H,dh,S]
  float* h32  = (float*)carve((size_t)32768 * 256 * 4);      // residual fp32
  float* lin  = (float*)carve((size_t)32768 * 256 * 4);      // o-proj/ff2 fp32
  u16* h16    = (u16*)carve((size_t)32768 * 256 * 2);        // bf16 GEMM input
  // CH=32: 67 MB score chunk stays Infinity-Cache-resident (CH=128 spills L3)
  const int CH = 32;
  u16* ff1    = (u16*)carve((size_t)32768 * 1024 * 2);       // ff1 out / scores
  u16* o16    = h16;   // attention-out reuses h16 (qkv already consumed it)
  u16* scores = ff1;   // 32-pair score chunk aliases ff1

  // weight conversions (fp32 -> bf16)
  cvt_k<<<dim3(512), dim3(256), 0, stream>>>(Wread, wrd16, 131072);
  cvt_k<<<dim3(1536), dim3(256), 0, stream>>>(Wqkv, wqkv16, 393216);
  cvt_k<<<dim3(512), dim3(256), 0, stream>>>(Wo, wo16, 131072);
  cvt_k<<<dim3(2048), dim3(256), 0, stream>>>(W1, w116, 524288);
  cvt_k<<<dim3(2048), dim3(256), 0, stream>>>(W2, w216, 524288);

  reservoir_k<<<dim3(32), dim3(64), 0, stream>>>(x, Win, Wres, z);

  // readout: h = z @ Wread^T + bread  (dual fp32 + bf16)
  gemm_bt<2, 2, MODE_DUAL><<<dim3(2, 256, 1), dim3(256), 0, stream>>>(
      z, wrd16, bread, h32, h16, nullptr, 512, 512, 512, 256, 0, 0, 0, 0, 1.0f, 0);

  for (int l = 0; l < 2; ++l) {
    // qkv + scatter into q_s / k_s / v_t
    gemm_bt<2, 2, MODE_QKV><<<dim3(6, 256, 1), dim3(256), 0, stream>>>(
        h16, wqkv16 + (size_t)l * 196608, bqkv + l * 768, q_s, k_s, v_t, 256,
        256, 256, 0, 0, 0, 0, 0, 1.0f, 0);
    // attention in chunks of CH (b,h)-pairs
    for (int ch = 0; ch < 128; ch += CH) {
      gemm_bt<2, 2, MODE_BF16><<<dim3(8, 8, CH), dim3(256), 0, stream>>>(
          q_s + (size_t)ch * 65536, k_s + (size_t)ch * 65536, nullptr, scores,
          nullptr, nullptr, 64, 64, 64, 1024, 65536, 65536, 1048576, 0,
          0.125f, 0);
      softmax_k<<<dim3(256 * CH), dim3(256), 0, stream>>>(scores);
      gemm_bt<2, 1, MODE_AVC><<<dim3(1, 8, CH), dim3(128), 0, stream>>>(
          scores, v_t + (size_t)ch * 65536, nullptr, o16, nullptr, nullptr,
          1024, 1024, 1024, 0, 1048576, 65536, 0, ch, 1.0f, 0);
    }
    // o-projection -> fp32 lin
    gemm_bt<2, 2, MODE_F32><<<dim3(2, 256, 1), dim3(256), 0, stream>>>(
        o16, wo16 + (size_t)l * 65536, bo + l * 256, lin, nullptr, nullptr,
        256, 256, 256, 256, 0, 0, 0, 0, 1.0f, 0);
    // LN1(h + o)
    ln_k<<<dim3(8192), dim3(256), 0, stream>>>(h32, lin, g1 + l * 256,
                                               b1 + l * 256, h32, h16);
    // FF1 + relu
    gemm_bt<2, 2, MODE_BF16><<<dim3(8, 256, 1), dim3(256), 0, stream>>>(
        h16, w116 + (size_t)l * 262144, c1 + l * 1024, ff1, nullptr, nullptr,
        256, 256, 256, 1024, 0, 0, 0, 0, 1.0f, 1);
    // FF2 -> fp32 lin
    gemm_bt<2, 2, MODE_F32><<<dim3(2, 256, 1), dim3(256), 0, stream>>>(
        ff1, w216 + (size_t)l * 262144, c2 + l * 256, lin, nullptr, nullptr,
        1024, 1024, 1024, 256, 0, 0, 0, 0, 1.0f, 0);
    // LN2(x + ff); final layer writes fp32 straight to d_out
    float* y32 = (l == 1) ? (float*)d_out : h32;
    u16* y16 = (l == 1) ? nullptr : h16;
    ln_k<<<dim3(8192), dim3(256), 0, stream>>>(h32, lin, g2 + l * 256,
                                               b2 + l * 256, y32, y16);
  }
}

// Round 7
// 1588.959 us; speedup vs baseline: 1.4363x; 1.0537x over previous
//
#include <hip/hip_runtime.h>
#include <stdint.h>

using short8  = __attribute__((ext_vector_type(8))) short;
using floatx4 = __attribute__((ext_vector_type(4))) float;

typedef unsigned short u16;
typedef unsigned int u32;
typedef unsigned long long u64;

#define AS1(p) ((const __attribute__((address_space(1))) void*)(p))
#define AS3(p) ((__attribute__((address_space(3))) void*)(p))

__device__ __forceinline__ float bs2f(u16 u) { return __uint_as_float(((u32)u) << 16); }
__device__ __forceinline__ u16 f2bs(float f) {
  u32 x = __float_as_uint(f);
  x += 0x7FFFu + ((x >> 16) & 1u);   // RNE
  return (u16)(x >> 16);
}
__device__ __forceinline__ float lo16(u32 u) { return __uint_as_float(u << 16); }
__device__ __forceinline__ float hi16(u32 u) { return __uint_as_float(u & 0xFFFF0000u); }

// ---------------------------------------------------------------------------
// fp32 -> bf16 weight conversion (RNE)
// ---------------------------------------------------------------------------
__global__ __launch_bounds__(256) void cvt_k(const float* __restrict__ src,
                                             u16* __restrict__ dst, int n) {
  int i = blockIdx.x * 256 + threadIdx.x;
  if (i < n) dst[i] = f2bs(src[i]);
}

// ---------------------------------------------------------------------------
// inp[row, r] = sum_k x[row, k] * Win[k, r]   (fp32, fmaf k-ascending —
// bitwise-identical to the previous in-loop accumulation order)
// ---------------------------------------------------------------------------
__global__ __launch_bounds__(512) void inp_k(const float* __restrict__ x,
                                             const float* __restrict__ Win,
                                             float* __restrict__ inp) {
  const int row = blockIdx.x;
  const int r = threadIdx.x;
  const float* xr = x + (size_t)row * 8;
  float s = 0.f;
#pragma unroll
  for (int k = 0; k < 8; ++k) s = fmaf(Win[k * 512 + r], xr[k], s);
  inp[(size_t)row * 512 + r] = s;
}

// ---------------------------------------------------------------------------
// LIF reservoir, single-wave: 32 blocks (1/batch) x 64 threads, lane c owns
// neurons 8c..8c+7. Input currents precomputed (inp_k). Fast path does ONE
// ballot/step (per-lane toggle flag); full 512-bit masks are reconstructed
// only inside the rare toggle branch. inp is register-double-buffered 8
// steps ahead. No barriers anywhere. State math exact fp32, same op order
// as rounds 2-6 (bitwise-stable).
// ---------------------------------------------------------------------------
__global__ __launch_bounds__(64) void reservoir_k(
    const float* __restrict__ inp,  // [32,1024,512] fp32
    const float* __restrict__ Wres, // [512,512]
    u16* __restrict__ zout)         // [32,1024,512] bf16 (0.0/1.0, exact)
{
  const int b = blockIdx.x;
  const int c = threadIdx.x & 63;
  const float* ib = inp + (size_t)b * 524288 + c * 8;
  u16* zb = zout + (size_t)b * 524288 + c * 8;
  float v[8] = {}, ci[8] = {}, rec[8] = {};
  u32 pz = 0;
  float4 pa[8], pc[8];
#pragma unroll
  for (int u = 0; u < 8; ++u) {
    pa[u] = *(const float4*)(ib + (size_t)u * 512);
    pc[u] = *(const float4*)(ib + (size_t)u * 512 + 4);
  }
  for (int tb = 0; tb < 128; ++tb) {
    float4 na[8], nc[8];
    if (tb < 127) {
      const float* nb = ib + (size_t)(tb + 1) * 4096;
#pragma unroll
      for (int u = 0; u < 8; ++u) {
        na[u] = *(const float4*)(nb + (size_t)u * 512);
        nc[u] = *(const float4*)(nb + (size_t)u * 512 + 4);
      }
    }
#pragma unroll
    for (int u = 0; u < 8; ++u) {
      const int t = tb * 8 + u;
      const float in[8] = {pa[u].x, pa[u].y, pa[u].z, pa[u].w,
                           pc[u].x, pc[u].y, pc[u].z, pc[u].w};
      u32 nzb = 0;
      u32 zw[4];
#pragma unroll
      for (int j = 0; j < 8; ++j) {
        // v_dec = v + 0.004*(-v + i)   (i = value from previous step)
        const float vdec = __fadd_rn(v[j], __fmul_rn(0.004f, __fadd_rn(-v[j], ci[j])));
        const int zc = (__fadd_rn(vdec, -0.1f) > 0.f) ? 1 : 0;
        v[j] = zc ? 0.f : vdec;
        nzb |= (u32)zc << j;
        // i_new = i*0.8 + (cur + rec),  rec corresponds to z_{t-1}
        ci[j] = __fadd_rn(__fmul_rn(ci[j], 0.8f), __fadd_rn(in[j], rec[j]));
        if (j & 1) zw[j >> 1] |= zc ? 0x3F800000u : 0u;
        else       zw[j >> 1]  = zc ? 0x3F80u : 0u;
      }
      *(uint4*)(zb + (size_t)t * 512) = make_uint4(zw[0], zw[1], zw[2], zw[3]);
      const u64 anyt = __ballot((nzb ^ pz) != 0);
      if (anyt) {                    // uniform branch; rare after ignition
#pragma unroll
        for (int j = 0; j < 8; ++j) {
          const u64 nm = __ballot((nzb >> j) & 1);
          const u64 pm = __ballot((pz >> j) & 1);
          u64 on   = nm & ~pm;
          u64 offm = pm & ~nm;
          while (on) {
            const int cc = __builtin_ctzll(on); on &= on - 1;
            const float* wr = Wres + ((size_t)(cc * 8 + j) << 9) + c * 8;
            const float4 w0 = *(const float4*)wr;
            const float4 w1 = *(const float4*)(wr + 4);
            rec[0] += w0.x; rec[1] += w0.y; rec[2] += w0.z; rec[3] += w0.w;
            rec[4] += w1.x; rec[5] += w1.y; rec[6] += w1.z; rec[7] += w1.w;
          }
          while (offm) {
            const int cc = __builtin_ctzll(offm); offm &= offm - 1;
            const float* wr = Wres + ((size_t)(cc * 8 + j) << 9) + c * 8;
            const float4 w0 = *(const float4*)wr;
            const float4 w1 = *(const float4*)(wr + 4);
            rec[0] -= w0.x; rec[1] -= w0.y; rec[2] -= w0.z; rec[3] -= w0.w;
            rec[4] -= w1.x; rec[5] -= w1.y; rec[6] -= w1.z; rec[7] -= w1.w;
          }
        }
      }
      pz = nzb;
    }
    if (tb < 127) {
#pragma unroll
      for (int u = 0; u < 8; ++u) { pa[u] = na[u]; pc[u] = nc[u]; }
    }
  }
}

// ---------------------------------------------------------------------------
// Generic bf16 MFMA GEMM: C = epilogue(A @ B^T * scale + bias)
// A [M,K] row-major (lda), B [N,K] row-major (ldb), both bf16. fp32 bias.
// BK=32, tile BM=WM*64, BN=WN*64, 4x4 16x16x32 frags/wave.
// m97-style: async global->LDS staging (width 16), LDS stride = BK (no pad).
// ---------------------------------------------------------------------------
enum { MODE_BF16 = 0, MODE_F32 = 1, MODE_DUAL = 2, MODE_QKV = 3, MODE_AVC = 4 };

template <int WM, int WN, int MODE>
__global__ __launch_bounds__(WM * WN * 64) void gemm_bt(
    const u16* __restrict__ A, const u16* __restrict__ B,
    const float* __restrict__ bias, void* __restrict__ C0,
    void* __restrict__ C1, void* __restrict__ C2, int K, int lda, int ldb,
    int ldc, long long sA, long long sB, long long sC, int pair0, float scale,
    int relu)
{
  constexpr int BM = WM * 64, BN = WN * 64, BK = 32;
  constexpr int NT = WM * WN * 64;
  constexpr int CA = BM * 4 / NT, CB = BN * 4 / NT;  // 16B chunks per thread
  __shared__ __align__(16) u16 As[BM * BK];
  __shared__ __align__(16) u16 Bs[BN * BK];
  const int tid = threadIdx.x;
  const int bz = blockIdx.z;
  const u16* Ab = A + (size_t)bz * sA + (size_t)blockIdx.y * BM * lda;
  const u16* Bb = B + (size_t)bz * sB + (size_t)blockIdx.x * BN * ldb;
  const int wavei = tid >> 6, lane = tid & 63;
  const int r16 = lane & 15, quad = lane >> 4;
  const int wm = (wavei % WM) * 64, wn = (wavei / WM) * 64;
  floatx4 acc[4][4] = {};
  for (int k0 = 0; k0 < K; k0 += BK) {
#pragma unroll
    for (int c = 0; c < CA; ++c) {
      const int idx = c * NT + tid;
      const int row = idx >> 2, kc = (idx & 3) << 3;
      __builtin_amdgcn_global_load_lds(AS1(Ab + (size_t)row * lda + k0 + kc),
                                       AS3(As + idx * 8), 16, 0, 0);
    }
#pragma unroll
    for (int c = 0; c < CB; ++c) {
      const int idx = c * NT + tid;
      const int row = idx >> 2, kc = (idx & 3) << 3;
      __builtin_amdgcn_global_load_lds(AS1(Bb + (size_t)row * ldb + k0 + kc),
                                       AS3(Bs + idx * 8), 16, 0, 0);
    }
    __syncthreads();
    short8 af[4], bfr[4];
#pragma unroll
    for (int i = 0; i < 4; ++i)
      af[i] = *(const short8*)&As[(wm + i * 16 + r16) * BK + quad * 8];
#pragma unroll
    for (int i = 0; i < 4; ++i)
      bfr[i] = *(const short8*)&Bs[(wn + i * 16 + r16) * BK + quad * 8];
#pragma unroll
    for (int i = 0; i < 4; ++i)
#pragma unroll
      for (int j = 0; j < 4; ++j)
        acc[i][j] = __builtin_amdgcn_mfma_f32_16x16x32_bf16(af[i], bfr[j], acc[i][j], 0, 0, 0);
    __syncthreads();
  }
#pragma unroll
  for (int i = 0; i < 4; ++i) {
#pragma unroll
    for (int j = 0; j < 4; ++j) {
#pragma unroll
      for (int q = 0; q < 4; ++q) {
        const int m = blockIdx.y * BM + wm + i * 16 + quad * 4 + q;
        const int n = blockIdx.x * BN + wn + j * 16 + r16;
        float val = acc[i][j][q] * scale;
        if (bias) val += bias[n];
        if (relu) val = fmaxf(val, 0.f);
        if constexpr (MODE == MODE_BF16) {
          ((u16*)C0)[(size_t)bz * sC + (size_t)m * ldc + n] = f2bs(val);
        } else if constexpr (MODE == MODE_F32) {
          ((float*)C0)[(size_t)m * ldc + n] = val;
        } else if constexpr (MODE == MODE_DUAL) {
          ((float*)C0)[(size_t)m * ldc + n] = val;
          ((u16*)C1)[(size_t)m * ldc + n] = f2bs(val);
        } else if constexpr (MODE == MODE_QKV) {
          const int b = m >> 10, s = m & 1023;
          const u16 outv = f2bs(val);
          const int h = (n & 255) >> 6, d = n & 63;
          if (n < 256)
            ((u16*)C0)[(((size_t)(b * 4 + h)) * 1024 + s) * 64 + d] = outv;  // q [B,H,S,dh]
          else if (n < 512)
            ((u16*)C1)[(((size_t)(b * 4 + h)) * 1024 + s) * 64 + d] = outv;  // k [B,H,S,dh]
          else
            ((u16*)C2)[(((size_t)(b * 4 + h)) * 64 + d) * 1024 + s] = outv;  // v^T [B,H,dh,S]
        } else if constexpr (MODE == MODE_AVC) {
          const int p = pair0 + bz;
          const size_t coff = (size_t)(p >> 2) * 262144 + (size_t)(p & 3) * 64;
          ((u16*)C0)[coff + (size_t)m * 256 + n] = f2bs(val);  // merged [B*S, H*dh]
        }
      }
    }
  }
}

// ---------------------------------------------------------------------------
// Row softmax over 1024 bf16, in place. One wave per row (16 elems/lane).
// ---------------------------------------------------------------------------
__global__ __launch_bounds__(256) void softmax_k(u16* __restrict__ s) {
  const int row = blockIdx.x * 4 + (threadIdx.x >> 6);
  const int lane = threadIdx.x & 63;
  u16* p = s + (size_t)row * 1024 + lane * 16;
  const uint4 u0 = *(const uint4*)p;
  const uint4 u1 = *(const uint4*)(p + 8);
  float f[16] = {lo16(u0.x), hi16(u0.x), lo16(u0.y), hi16(u0.y),
                 lo16(u0.z), hi16(u0.z), lo16(u0.w), hi16(u0.w),
                 lo16(u1.x), hi16(u1.x), lo16(u1.y), hi16(u1.y),
                 lo16(u1.z), hi16(u1.z), lo16(u1.w), hi16(u1.w)};
  float mx = f[0];
#pragma unroll
  for (int i = 1; i < 16; ++i) mx = fmaxf(mx, f[i]);
#pragma unroll
  for (int off = 32; off > 0; off >>= 1) mx = fmaxf(mx, __shfl_xor(mx, off));
  float sum = 0.f;
#pragma unroll
  for (int i = 0; i < 16; ++i) { f[i] = __expf(f[i] - mx); sum += f[i]; }
#pragma unroll
  for (int off = 32; off > 0; off >>= 1) sum += __shfl_xor(sum, off);
  const float inv = 1.f / sum;
  u32 o[8];
#pragma unroll
  for (int i = 0; i < 8; ++i)
    o[i] = (u32)f2bs(f[2 * i] * inv) | ((u32)f2bs(f[2 * i + 1] * inv) << 16);
  *(uint4*)p = make_uint4(o[0], o[1], o[2], o[3]);
  *(uint4*)(p + 8) = make_uint4(o[4], o[5], o[6], o[7]);
}

// ---------------------------------------------------------------------------
// Fused residual-add + LayerNorm over 256 fp32; writes fp32 and/or bf16.
// One wave per row (4 elems/lane).
// ---------------------------------------------------------------------------
__global__ __launch_bounds__(256) void ln_k(const float* __restrict__ x,
                                            const float* __restrict__ add,
                                            const float* __restrict__ g,
                                            const float* __restrict__ bta,
                                            float* __restrict__ y32,
                                            u16* __restrict__ y16) {
  const int row = blockIdx.x * 4 + (threadIdx.x >> 6);
  const int lane = threadIdx.x & 63;
  const size_t base = (size_t)row * 256 + lane * 4;
  const float4 xv = *(const float4*)(x + base);
  const float4 av = *(const float4*)(add + base);
  float sv[4] = {xv.x + av.x, xv.y + av.y, xv.z + av.z, xv.w + av.w};
  float sum = sv[0] + sv[1] + sv[2] + sv[3];
#pragma unroll
  for (int off = 32; off > 0; off >>= 1) sum += __shfl_xor(sum, off);
  const float mean = sum * (1.f / 256.f);
  float var = 0.f;
  float d[4];
#pragma unroll
  for (int i = 0; i < 4; ++i) { d[i] = sv[i] - mean; var += d[i] * d[i]; }
#pragma unroll
  for (int off = 32; off > 0; off >>= 1) var += __shfl_xor(var, off);
  var *= (1.f / 256.f);
  const float inv = 1.f / sqrtf(var + 1e-5f);
  float yv[4];
#pragma unroll
  for (int i = 0; i < 4; ++i)
    yv[i] = d[i] * inv * g[lane * 4 + i] + bta[lane * 4 + i];
  if (y32) *(float4*)(y32 + base) = make_float4(yv[0], yv[1], yv[2], yv[3]);
  if (y16) {
    const u32 p0 = (u32)f2bs(yv[0]) | ((u32)f2bs(yv[1]) << 16);
    const u32 p1 = (u32)f2bs(yv[2]) | ((u32)f2bs(yv[3]) << 16);
    *(uint2*)(y16 + base) = make_uint2(p0, p1);
  }
}

// ---------------------------------------------------------------------------
extern "C" void kernel_launch(void* const* d_in, const int* in_sizes, int n_in,
                              void* d_out, int out_size, void* d_ws,
                              size_t ws_size, hipStream_t stream) {
  (void)in_sizes; (void)n_in; (void)out_size; (void)ws_size;
  const float* x     = (const float*)d_in[0];   // [32,1024,8]
  const float* Win   = (const float*)d_in[1];   // [8,512]
  const float* Wres  = (const float*)d_in[2];   // [512,512]
  const float* Wread = (const float*)d_in[3];   // [256,512]
  const float* bread = (const float*)d_in[4];   // [256]
  const float* Wqkv  = (const float*)d_in[5];   // [2,768,256]
  const float* bqkv  = (const float*)d_in[6];   // [2,768]
  const float* Wo    = (const float*)d_in[7];   // [2,256,256]
  const float* bo    = (const float*)d_in[8];   // [2,256]
  const float* g1    = (const float*)d_in[9];
  const float* b1    = (const float*)d_in[10];
  const float* g2    = (const float*)d_in[11];
  const float* b2    = (const float*)d_in[12];
  const float* W1    = (const float*)d_in[13];  // [2,1024,256]
  const float* c1    = (const float*)d_in[14];  // [2,1024]
  const float* W2    = (const float*)d_in[15];  // [2,256,1024]
  const float* c2    = (const float*)d_in[16];  // [2,256]

  char* ws = (char*)d_ws;
  size_t off = 0;
  auto carve = [&](size_t bytes) {
    char* p = ws + off;
    off += (bytes + 255) & ~(size_t)255;
    return p;
  };
  u16* z      = (u16*)carve((size_t)32 * 1024 * 512 * 2);    // 33.6 MB spikes (bf16)
  u16* wrd16  = (u16*)carve((size_t)256 * 512 * 2);          // bf16 weights:
  u16* wqkv16 = (u16*)carve((size_t)2 * 768 * 256 * 2);
  u16* wo16   = (u16*)carve((size_t)2 * 256 * 256 * 2);
  u16* w116   = (u16*)carve((size_t)2 * 1024 * 256 * 2);
  u16* w216   = (u16*)carve((size_t)2 * 256 * 1024 * 2);
  u16* q_s    = (u16*)carve((size_t)128 * 1024 * 64 * 2);    // [B*H,S,dh]
  u16* k_s    = (u16*)carve((size_t)128 * 1024 * 64 * 2);
  u16* v_t    = (u16*)carve((size_t)128 * 64 * 1024 * 2);    // [B*H,dh,S]
  float* h32  = (float*)carve((size_t)32768 * 256 * 4);      // residual fp32
  float* lin  = (float*)carve((size_t)32768 * 256 * 4);      // o-proj/ff2 fp32
  u16* h16    = (u16*)carve((size_t)32768 * 256 * 2);        // bf16 GEMM input
  // CH=32: 67 MB score chunk stays Infinity-Cache-resident
  const int CH = 32;
  u16* ff1    = (u16*)carve((size_t)32768 * 1024 * 2);       // ff1 out / scores
  u16* o16    = h16;   // attention-out reuses h16 (qkv already consumed it)
  u16* scores = ff1;   // 32-pair score chunk aliases ff1
  float* inp  = (float*)ff1;  // 67.1 MB precomputed input currents (dead
                              // before the transformer loop starts)

  // weight conversions (fp32 -> bf16)
  cvt_k<<<dim3(512), dim3(256), 0, stream>>>(Wread, wrd16, 131072);
  cvt_k<<<dim3(1536), dim3(256), 0, stream>>>(Wqkv, wqkv16, 393216);
  cvt_k<<<dim3(512), dim3(256), 0, stream>>>(Wo, wo16, 131072);
  cvt_k<<<dim3(2048), dim3(256), 0, stream>>>(W1, w116, 524288);
  cvt_k<<<dim3(2048), dim3(256), 0, stream>>>(W2, w216, 524288);

  inp_k<<<dim3(32768), dim3(512), 0, stream>>>(x, Win, inp);
  reservoir_k<<<dim3(32), dim3(64), 0, stream>>>(inp, Wres, z);

  // readout: h = z @ Wread^T + bread  (dual fp32 + bf16)
  gemm_bt<2, 2, MODE_DUAL><<<dim3(2, 256, 1), dim3(256), 0, stream>>>(
      z, wrd16, bread, h32, h16, nullptr, 512, 512, 512, 256, 0, 0, 0, 0, 1.0f, 0);

  for (int l = 0; l < 2; ++l) {
    // qkv + scatter into q_s / k_s / v_t
    gemm_bt<2, 2, MODE_QKV><<<dim3(6, 256, 1), dim3(256), 0, stream>>>(
        h16, wqkv16 + (size_t)l * 196608, bqkv + l * 768, q_s, k_s, v_t, 256,
        256, 256, 0, 0, 0, 0, 0, 1.0f, 0);
    // attention in chunks of CH (b,h)-pairs
    for (int ch = 0; ch < 128; ch += CH) {
      gemm_bt<2, 2, MODE_BF16><<<dim3(8, 8, CH), dim3(256), 0, stream>>>(
          q_s + (size_t)ch * 65536, k_s + (size_t)ch * 65536, nullptr, scores,
          nullptr, nullptr, 64, 64, 64, 1024, 65536, 65536, 1048576, 0,
          0.125f, 0);
      softmax_k<<<dim3(256 * CH), dim3(256), 0, stream>>>(scores);
      gemm_bt<2, 1, MODE_AVC><<<dim3(1, 8, CH), dim3(128), 0, stream>>>(
          scores, v_t + (size_t)ch * 65536, nullptr, o16, nullptr, nullptr,
          1024, 1024, 1024, 0, 1048576, 65536, 0, ch, 1.0f, 0);
    }
    // o-projection -> fp32 lin
    gemm_bt<2, 2, MODE_F32><<<dim3(2, 256, 1), dim3(256), 0, stream>>>(
        o16, wo16 + (size_t)l * 65536, bo + l * 256, lin, nullptr, nullptr,
        256, 256, 256, 256, 0, 0, 0, 0, 1.0f, 0);
    // LN1(h + o)
    ln_k<<<dim3(8192), dim3(256), 0, stream>>>(h32, lin, g1 + l * 256,
                                               b1 + l * 256, h32, h16);
    // FF1 + relu
    gemm_bt<2, 2, MODE_BF16><<<dim3(8, 256, 1), dim3(256), 0, stream>>>(
        h16, w116 + (size_t)l * 262144, c1 + l * 1024, ff1, nullptr, nullptr,
        256, 256, 256, 1024, 0, 0, 0, 0, 1.0f, 1);
    // FF2 -> fp32 lin
    gemm_bt<2, 2, MODE_F32><<<dim3(2, 256, 1), dim3(256), 0, stream>>>(
        ff1, w216 + (size_t)l * 262144, c2 + l * 256, lin, nullptr, nullptr,
        1024, 1024, 1024, 256, 0, 0, 0, 0, 1.0f, 0);
    // LN2(x + ff); final layer writes fp32 straight to d_out
    float* y32 = (l == 1) ? (float*)d_out : h32;
    u16* y16 = (l == 1) ? nullptr : h16;
    ln_k<<<dim3(8192), dim3(256), 0, stream>>>(h32, lin, g2 + l * 256,
                                               b2 + l * 256, y32, y16);
  }
}

// Round 8
// 1331.826 us; speedup vs baseline: 1.7136x; 1.1931x over previous
//
#include <hip/hip_runtime.h>
#include <stdint.h>

using short8  = __attribute__((ext_vector_type(8))) short;
using floatx4 = __attribute__((ext_vector_type(4))) float;

typedef unsigned short u16;
typedef unsigned int u32;
typedef unsigned long long u64;

#define AS1(p) ((const __attribute__((address_space(1))) void*)(p))
#define AS3(p) ((__attribute__((address_space(3))) void*)(p))

__device__ __forceinline__ float bs2f(u16 u) { return __uint_as_float(((u32)u) << 16); }
__device__ __forceinline__ u16 f2bs(float f) {
  u32 x = __float_as_uint(f);
  x += 0x7FFFu + ((x >> 16) & 1u);   // RNE
  return (u16)(x >> 16);
}
__device__ __forceinline__ float lo16(u32 u) { return __uint_as_float(u << 16); }
__device__ __forceinline__ float hi16(u32 u) { return __uint_as_float(u & 0xFFFF0000u); }

// ---------------------------------------------------------------------------
// fp32 -> bf16 weight conversion (RNE)
// ---------------------------------------------------------------------------
__global__ __launch_bounds__(256) void cvt_k(const float* __restrict__ src,
                                             u16* __restrict__ dst, int n) {
  int i = blockIdx.x * 256 + threadIdx.x;
  if (i < n) dst[i] = f2bs(src[i]);
}

// ---------------------------------------------------------------------------
// inp[row, r] = sum_k x[row, k] * Win[k, r]   (fp32, fmaf k-ascending)
// ---------------------------------------------------------------------------
__global__ __launch_bounds__(512) void inp_k(const float* __restrict__ x,
                                             const float* __restrict__ Win,
                                             float* __restrict__ inp) {
  const int row = blockIdx.x;
  const int r = threadIdx.x;
  const float* xr = x + (size_t)row * 8;
  float s = 0.f;
#pragma unroll
  for (int k = 0; k < 8; ++k) s = fmaf(Win[k * 512 + r], xr[k], s);
  inp[(size_t)row * 512 + r] = s;
}

// ---------------------------------------------------------------------------
// LIF reservoir, single-wave: 32 blocks (1/batch) x 64 threads, lane c owns
// neurons 8c..8c+7. Input currents precomputed (inp_k), reg-double-buffered.
// ONE ballot/step fast path; full masks reconstructed only on toggles.
// No barriers. Exact fp32, same op order as rounds 2-7 (bitwise-stable).
// ---------------------------------------------------------------------------
__global__ __launch_bounds__(64) void reservoir_k(
    const float* __restrict__ inp,  // [32,1024,512] fp32
    const float* __restrict__ Wres, // [512,512]
    u16* __restrict__ zout)         // [32,1024,512] bf16 (0.0/1.0, exact)
{
  const int b = blockIdx.x;
  const int c = threadIdx.x & 63;
  const float* ib = inp + (size_t)b * 524288 + c * 8;
  u16* zb = zout + (size_t)b * 524288 + c * 8;
  float v[8] = {}, ci[8] = {}, rec[8] = {};
  u32 pz = 0;
  float4 pa[8], pc[8];
#pragma unroll
  for (int u = 0; u < 8; ++u) {
    pa[u] = *(const float4*)(ib + (size_t)u * 512);
    pc[u] = *(const float4*)(ib + (size_t)u * 512 + 4);
  }
  for (int tb = 0; tb < 128; ++tb) {
    float4 na[8], nc[8];
    if (tb < 127) {
      const float* nb = ib + (size_t)(tb + 1) * 4096;
#pragma unroll
      for (int u = 0; u < 8; ++u) {
        na[u] = *(const float4*)(nb + (size_t)u * 512);
        nc[u] = *(const float4*)(nb + (size_t)u * 512 + 4);
      }
    }
#pragma unroll
    for (int u = 0; u < 8; ++u) {
      const int t = tb * 8 + u;
      const float in[8] = {pa[u].x, pa[u].y, pa[u].z, pa[u].w,
                           pc[u].x, pc[u].y, pc[u].z, pc[u].w};
      u32 nzb = 0;
      u32 zw[4];
#pragma unroll
      for (int j = 0; j < 8; ++j) {
        const float vdec = __fadd_rn(v[j], __fmul_rn(0.004f, __fadd_rn(-v[j], ci[j])));
        const int zc = (__fadd_rn(vdec, -0.1f) > 0.f) ? 1 : 0;
        v[j] = zc ? 0.f : vdec;
        nzb |= (u32)zc << j;
        ci[j] = __fadd_rn(__fmul_rn(ci[j], 0.8f), __fadd_rn(in[j], rec[j]));
        if (j & 1) zw[j >> 1] |= zc ? 0x3F800000u : 0u;
        else       zw[j >> 1]  = zc ? 0x3F80u : 0u;
      }
      *(uint4*)(zb + (size_t)t * 512) = make_uint4(zw[0], zw[1], zw[2], zw[3]);
      const u64 anyt = __ballot((nzb ^ pz) != 0);
      if (anyt) {
#pragma unroll
        for (int j = 0; j < 8; ++j) {
          const u64 nm = __ballot((nzb >> j) & 1);
          const u64 pm = __ballot((pz >> j) & 1);
          u64 on   = nm & ~pm;
          u64 offm = pm & ~nm;
          while (on) {
            const int cc = __builtin_ctzll(on); on &= on - 1;
            const float* wr = Wres + ((size_t)(cc * 8 + j) << 9) + c * 8;
            const float4 w0 = *(const float4*)wr;
            const float4 w1 = *(const float4*)(wr + 4);
            rec[0] += w0.x; rec[1] += w0.y; rec[2] += w0.z; rec[3] += w0.w;
            rec[4] += w1.x; rec[5] += w1.y; rec[6] += w1.z; rec[7] += w1.w;
          }
          while (offm) {
            const int cc = __builtin_ctzll(offm); offm &= offm - 1;
            const float* wr = Wres + ((size_t)(cc * 8 + j) << 9) + c * 8;
            const float4 w0 = *(const float4*)wr;
            const float4 w1 = *(const float4*)(wr + 4);
            rec[0] -= w0.x; rec[1] -= w0.y; rec[2] -= w0.z; rec[3] -= w0.w;
            rec[4] -= w1.x; rec[5] -= w1.y; rec[6] -= w1.z; rec[7] -= w1.w;
          }
        }
      }
      pz = nzb;
    }
    if (tb < 127) {
#pragma unroll
      for (int u = 0; u < 8; ++u) { pa[u] = na[u]; pc[u] = nc[u]; }
    }
  }
}

// ---------------------------------------------------------------------------
// Generic bf16 MFMA GEMM: C = epilogue(A @ B^T * scale + bias)
// ---------------------------------------------------------------------------
enum { MODE_BF16 = 0, MODE_F32 = 1, MODE_DUAL = 2, MODE_QKV = 3 };

template <int WM, int WN, int MODE>
__global__ __launch_bounds__(WM * WN * 64) void gemm_bt(
    const u16* __restrict__ A, const u16* __restrict__ B,
    const float* __restrict__ bias, void* __restrict__ C0,
    void* __restrict__ C1, void* __restrict__ C2, int K, int lda, int ldb,
    int ldc, long long sA, long long sB, long long sC, float scale, int relu)
{
  constexpr int BM = WM * 64, BN = WN * 64, BK = 32;
  constexpr int NT = WM * WN * 64;
  constexpr int CA = BM * 4 / NT, CB = BN * 4 / NT;
  __shared__ __align__(16) u16 As[BM * BK];
  __shared__ __align__(16) u16 Bs[BN * BK];
  const int tid = threadIdx.x;
  const int bz = blockIdx.z;
  const u16* Ab = A + (size_t)bz * sA + (size_t)blockIdx.y * BM * lda;
  const u16* Bb = B + (size_t)bz * sB + (size_t)blockIdx.x * BN * ldb;
  const int wavei = tid >> 6, lane = tid & 63;
  const int r16 = lane & 15, quad = lane >> 4;
  const int wm = (wavei % WM) * 64, wn = (wavei / WM) * 64;
  floatx4 acc[4][4] = {};
  for (int k0 = 0; k0 < K; k0 += BK) {
#pragma unroll
    for (int c = 0; c < CA; ++c) {
      const int idx = c * NT + tid;
      const int row = idx >> 2, kc = (idx & 3) << 3;
      __builtin_amdgcn_global_load_lds(AS1(Ab + (size_t)row * lda + k0 + kc),
                                       AS3(As + idx * 8), 16, 0, 0);
    }
#pragma unroll
    for (int c = 0; c < CB; ++c) {
      const int idx = c * NT + tid;
      const int row = idx >> 2, kc = (idx & 3) << 3;
      __builtin_amdgcn_global_load_lds(AS1(Bb + (size_t)row * ldb + k0 + kc),
                                       AS3(Bs + idx * 8), 16, 0, 0);
    }
    __syncthreads();
    short8 af[4], bfr[4];
#pragma unroll
    for (int i = 0; i < 4; ++i)
      af[i] = *(const short8*)&As[(wm + i * 16 + r16) * BK + quad * 8];
#pragma unroll
    for (int i = 0; i < 4; ++i)
      bfr[i] = *(const short8*)&Bs[(wn + i * 16 + r16) * BK + quad * 8];
#pragma unroll
    for (int i = 0; i < 4; ++i)
#pragma unroll
      for (int j = 0; j < 4; ++j)
        acc[i][j] = __builtin_amdgcn_mfma_f32_16x16x32_bf16(af[i], bfr[j], acc[i][j], 0, 0, 0);
    __syncthreads();
  }
#pragma unroll
  for (int i = 0; i < 4; ++i) {
#pragma unroll
    for (int j = 0; j < 4; ++j) {
#pragma unroll
      for (int q = 0; q < 4; ++q) {
        const int m = blockIdx.y * BM + wm + i * 16 + quad * 4 + q;
        const int n = blockIdx.x * BN + wn + j * 16 + r16;
        float val = acc[i][j][q] * scale;
        if (bias) val += bias[n];
        if (relu) val = fmaxf(val, 0.f);
        if constexpr (MODE == MODE_BF16) {
          ((u16*)C0)[(size_t)bz * sC + (size_t)m * ldc + n] = f2bs(val);
        } else if constexpr (MODE == MODE_F32) {
          ((float*)C0)[(size_t)m * ldc + n] = val;
        } else if constexpr (MODE == MODE_DUAL) {
          ((float*)C0)[(size_t)m * ldc + n] = val;
          ((u16*)C1)[(size_t)m * ldc + n] = f2bs(val);
        } else if constexpr (MODE == MODE_QKV) {
          const int b = m >> 10, s = m & 1023;
          const u16 outv = f2bs(val);
          const int h = (n & 255) >> 6, d = n & 63;
          if (n < 256)
            ((u16*)C0)[(((size_t)(b * 4 + h)) * 1024 + s) * 64 + d] = outv;  // q [BH,S,dh]
          else if (n < 512)
            ((u16*)C1)[(((size_t)(b * 4 + h)) * 1024 + s) * 64 + d] = outv;  // k [BH,S,dh]
          else
            ((u16*)C2)[(((size_t)(b * 4 + h)) * 64 + d) * 1024 + s] = outv;  // v^T [BH,dh,S]
        }
      }
    }
  }
}

// ---------------------------------------------------------------------------
// Flash attention: one block per (q-tile 128, pair). 4 waves x 32 q-rows.
// dh=64, S=1024, 8 key-tiles of 128. Online softmax, P via per-wave LDS
// roundtrip (C-layout write -> A-layout b128 read). V^T consumed as B-operand.
// K/V register-prefetched one tile ahead.
// ---------------------------------------------------------------------------
__global__ __launch_bounds__(256) void attn_k(
    const u16* __restrict__ q_s,  // [128,1024,64]
    const u16* __restrict__ k_s,  // [128,1024,64]
    const u16* __restrict__ v_t,  // [128,64,1024]
    u16* __restrict__ o16)        // [32768,256] merged
{
  constexpr int LQ = 72, LV = 136, LP = 136;   // padded u16 row strides
  __shared__ __align__(16) u16 Qs[128 * LQ];
  __shared__ __align__(16) u16 Ks[128 * LQ];
  __shared__ __align__(16) u16 Vt[64 * LV];
  __shared__ __align__(16) u16 Ps[128 * LP];
  const int tid = threadIdx.x;
  const int w = tid >> 6, lane = tid & 63;
  const int r16 = lane & 15, quad = lane >> 4;
  const int p = blockIdx.y;         // (b,h) pair
  const int q0 = blockIdx.x * 128;  // q-row base
  const u16* qg = q_s + ((size_t)p * 1024 + q0) * 64;
  const u16* kg = k_s + (size_t)p * 65536;
  const u16* vg = v_t + (size_t)p * 65536;

  // stage Q + K0 + V0
#pragma unroll
  for (int it = 0; it < 4; ++it) {
    const int idx = it * 256 + tid;
    const int row = idx >> 3, c8 = (idx & 7) * 8;
    *(uint4*)&Qs[row * LQ + c8] = *(const uint4*)(qg + (size_t)row * 64 + c8);
    *(uint4*)&Ks[row * LQ + c8] = *(const uint4*)(kg + (size_t)row * 64 + c8);
  }
#pragma unroll
  for (int it = 0; it < 4; ++it) {
    const int idx = it * 256 + tid;
    const int row = idx >> 4, c8 = (idx & 15) * 8;
    *(uint4*)&Vt[row * LV + c8] = *(const uint4*)(vg + (size_t)row * 1024 + c8);
  }
  __syncthreads();

  short8 aq[2][2];
#pragma unroll
  for (int i = 0; i < 2; ++i)
#pragma unroll
    for (int kc = 0; kc < 2; ++kc)
      aq[i][kc] = *(const short8*)&Qs[(w * 32 + i * 16 + r16) * LQ + kc * 32 + quad * 8];

  floatx4 o[2][4] = {};
  float mr[2][4], l[2][4];
#pragma unroll
  for (int i = 0; i < 2; ++i)
#pragma unroll
    for (int q = 0; q < 4; ++q) { mr[i][q] = -3e38f; l[i][q] = 0.f; }

  for (int kt = 0; kt < 8; ++kt) {
    uint4 kpre[4], vpre[4];
    if (kt < 7) {
      const u16* kgn = kg + (size_t)(kt + 1) * 128 * 64;
#pragma unroll
      for (int it = 0; it < 4; ++it) {
        const int idx = it * 256 + tid;
        kpre[it] = *(const uint4*)(kgn + (size_t)(idx >> 3) * 64 + (idx & 7) * 8);
        vpre[it] = *(const uint4*)(vg + (size_t)(idx >> 4) * 1024 + (kt + 1) * 128 + (idx & 15) * 8);
      }
    }
    // S = Q K^T * 0.125
    floatx4 s[2][8] = {};
#pragma unroll
    for (int kc = 0; kc < 2; ++kc) {
#pragma unroll
      for (int f = 0; f < 8; ++f) {
        const short8 bk = *(const short8*)&Ks[(f * 16 + r16) * LQ + kc * 32 + quad * 8];
#pragma unroll
        for (int i = 0; i < 2; ++i)
          s[i][f] = __builtin_amdgcn_mfma_f32_16x16x32_bf16(aq[i][kc], bk, s[i][f], 0, 0, 0);
      }
    }
#pragma unroll
    for (int i = 0; i < 2; ++i) {
      float mt[4] = {-3e38f, -3e38f, -3e38f, -3e38f};
#pragma unroll
      for (int f = 0; f < 8; ++f)
#pragma unroll
        for (int q = 0; q < 4; ++q) {
          s[i][f][q] *= 0.125f;
          mt[q] = fmaxf(mt[q], s[i][f][q]);
        }
#pragma unroll
      for (int off = 8; off > 0; off >>= 1)
#pragma unroll
        for (int q = 0; q < 4; ++q) mt[q] = fmaxf(mt[q], __shfl_xor(mt[q], off));
      float al[4], rs[4] = {};
#pragma unroll
      for (int q = 0; q < 4; ++q) {
        const float mn = fmaxf(mr[i][q], mt[q]);
        al[q] = __expf(mr[i][q] - mn);
        mr[i][q] = mn;
      }
#pragma unroll
      for (int f = 0; f < 8; ++f)
#pragma unroll
        for (int q = 0; q < 4; ++q) {
          const float pv = __expf(s[i][f][q] - mr[i][q]);
          s[i][f][q] = pv;
          rs[q] += pv;
        }
#pragma unroll
      for (int off = 8; off > 0; off >>= 1)
#pragma unroll
        for (int q = 0; q < 4; ++q) rs[q] += __shfl_xor(rs[q], off);
#pragma unroll
      for (int q = 0; q < 4; ++q) l[i][q] = l[i][q] * al[q] + rs[q];
#pragma unroll
      for (int n = 0; n < 4; ++n)
#pragma unroll
        for (int q = 0; q < 4; ++q) o[i][n][q] *= al[q];
      // P -> LDS (own wave region), bf16, C-layout positions
#pragma unroll
      for (int f = 0; f < 8; ++f)
#pragma unroll
        for (int q = 0; q < 4; ++q)
          Ps[(w * 32 + i * 16 + quad * 4 + q) * LP + f * 16 + r16] = f2bs(s[i][f][q]);
    }
    // O += P V   (A-frags from Ps, B-frags from Vt)
#pragma unroll
    for (int kc = 0; kc < 4; ++kc) {
      short8 ap[2];
#pragma unroll
      for (int i = 0; i < 2; ++i)
        ap[i] = *(const short8*)&Ps[(w * 32 + i * 16 + r16) * LP + kc * 32 + quad * 8];
#pragma unroll
      for (int n = 0; n < 4; ++n) {
        const short8 bv = *(const short8*)&Vt[(n * 16 + r16) * LV + kc * 32 + quad * 8];
#pragma unroll
        for (int i = 0; i < 2; ++i)
          o[i][n] = __builtin_amdgcn_mfma_f32_16x16x32_bf16(ap[i], bv, o[i][n], 0, 0, 0);
      }
    }
    __syncthreads();                  // everyone done reading Ks/Vt
    if (kt < 7) {
#pragma unroll
      for (int it = 0; it < 4; ++it) {
        const int idx = it * 256 + tid;
        *(uint4*)&Ks[(idx >> 3) * LQ + (idx & 7) * 8] = kpre[it];
        *(uint4*)&Vt[(idx >> 4) * LV + (idx & 15) * 8] = vpre[it];
      }
      __syncthreads();                // staged tile visible
    }
  }
  // epilogue: O / l -> merged [B*S, H*dh]
  const int bb = p >> 2, hh = p & 3;
#pragma unroll
  for (int i = 0; i < 2; ++i)
#pragma unroll
    for (int q = 0; q < 4; ++q) {
      const float inv = 1.f / l[i][q];
      const int srow = q0 + w * 32 + i * 16 + quad * 4 + q;
#pragma unroll
      for (int n = 0; n < 4; ++n)
        o16[((size_t)bb * 1024 + srow) * 256 + hh * 64 + n * 16 + r16] =
            f2bs(o[i][n][q] * inv);
    }
}

// ---------------------------------------------------------------------------
// Fused residual-add + LayerNorm over 256 fp32; writes fp32 and/or bf16.
// ---------------------------------------------------------------------------
__global__ __launch_bounds__(256) void ln_k(const float* __restrict__ x,
                                            const float* __restrict__ add,
                                            const float* __restrict__ g,
                                            const float* __restrict__ bta,
                                            float* __restrict__ y32,
                                            u16* __restrict__ y16) {
  const int row = blockIdx.x * 4 + (threadIdx.x >> 6);
  const int lane = threadIdx.x & 63;
  const size_t base = (size_t)row * 256 + lane * 4;
  const float4 xv = *(const float4*)(x + base);
  const float4 av = *(const float4*)(add + base);
  float sv[4] = {xv.x + av.x, xv.y + av.y, xv.z + av.z, xv.w + av.w};
  float sum = sv[0] + sv[1] + sv[2] + sv[3];
#pragma unroll
  for (int off = 32; off > 0; off >>= 1) sum += __shfl_xor(sum, off);
  const float mean = sum * (1.f / 256.f);
  float var = 0.f;
  float d[4];
#pragma unroll
  for (int i = 0; i < 4; ++i) { d[i] = sv[i] - mean; var += d[i] * d[i]; }
#pragma unroll
  for (int off = 32; off > 0; off >>= 1) var += __shfl_xor(var, off);
  var *= (1.f / 256.f);
  const float inv = 1.f / sqrtf(var + 1e-5f);
  float yv[4];
#pragma unroll
  for (int i = 0; i < 4; ++i)
    yv[i] = d[i] * inv * g[lane * 4 + i] + bta[lane * 4 + i];
  if (y32) *(float4*)(y32 + base) = make_float4(yv[0], yv[1], yv[2], yv[3]);
  if (y16) {
    const u32 p0 = (u32)f2bs(yv[0]) | ((u32)f2bs(yv[1]) << 16);
    const u32 p1 = (u32)f2bs(yv[2]) | ((u32)f2bs(yv[3]) << 16);
    *(uint2*)(y16 + base) = make_uint2(p0, p1);
  }
}

// ---------------------------------------------------------------------------
extern "C" void kernel_launch(void* const* d_in, const int* in_sizes, int n_in,
                              void* d_out, int out_size, void* d_ws,
                              size_t ws_size, hipStream_t stream) {
  (void)in_sizes; (void)n_in; (void)out_size; (void)ws_size;
  const float* x     = (const float*)d_in[0];
  const float* Win   = (const float*)d_in[1];
  const float* Wres  = (const float*)d_in[2];
  const float* Wread = (const float*)d_in[3];
  const float* bread = (const float*)d_in[4];
  const float* Wqkv  = (const float*)d_in[5];
  const float* bqkv  = (const float*)d_in[6];
  const float* Wo    = (const float*)d_in[7];
  const float* bo    = (const float*)d_in[8];
  const float* g1    = (const float*)d_in[9];
  const float* b1    = (const float*)d_in[10];
  const float* g2    = (const float*)d_in[11];
  const float* b2    = (const float*)d_in[12];
  const float* W1    = (const float*)d_in[13];
  const float* c1    = (const float*)d_in[14];
  const float* W2    = (const float*)d_in[15];
  const float* c2    = (const float*)d_in[16];

  char* ws = (char*)d_ws;
  size_t off = 0;
  auto carve = [&](size_t bytes) {
    char* p = ws + off;
    off += (bytes + 255) & ~(size_t)255;
    return p;
  };
  u16* z      = (u16*)carve((size_t)32 * 1024 * 512 * 2);
  u16* wrd16  = (u16*)carve((size_t)256 * 512 * 2);
  u16* wqkv16 = (u16*)carve((size_t)2 * 768 * 256 * 2);
  u16* wo16   = (u16*)carve((size_t)2 * 256 * 256 * 2);
  u16* w116   = (u16*)carve((size_t)2 * 1024 * 256 * 2);
  u16* w216   = (u16*)carve((size_t)2 * 256 * 1024 * 2);
  u16* q_s    = (u16*)carve((size_t)128 * 1024 * 64 * 2);
  u16* k_s    = (u16*)carve((size_t)128 * 1024 * 64 * 2);
  u16* v_t    = (u16*)carve((size_t)128 * 64 * 1024 * 2);
  float* h32  = (float*)carve((size_t)32768 * 256 * 4);
  float* lin  = (float*)carve((size_t)32768 * 256 * 4);
  u16* h16    = (u16*)carve((size_t)32768 * 256 * 2);
  u16* ff1    = (u16*)carve((size_t)32768 * 1024 * 2);   // ff1 out
  u16* o16    = h16;          // attention output reuses h16
  float* inp  = (float*)ff1;  // precomputed input currents (dead before ff1)

  cvt_k<<<dim3(512), dim3(256), 0, stream>>>(Wread, wrd16, 131072);
  cvt_k<<<dim3(1536), dim3(256), 0, stream>>>(Wqkv, wqkv16, 393216);
  cvt_k<<<dim3(512), dim3(256), 0, stream>>>(Wo, wo16, 131072);
  cvt_k<<<dim3(2048), dim3(256), 0, stream>>>(W1, w116, 524288);
  cvt_k<<<dim3(2048), dim3(256), 0, stream>>>(W2, w216, 524288);

  inp_k<<<dim3(32768), dim3(512), 0, stream>>>(x, Win, inp);
  reservoir_k<<<dim3(32), dim3(64), 0, stream>>>(inp, Wres, z);

  // readout: h = z @ Wread^T + bread  (dual fp32 + bf16)
  gemm_bt<2, 2, MODE_DUAL><<<dim3(2, 256, 1), dim3(256), 0, stream>>>(
      z, wrd16, bread, h32, h16, nullptr, 512, 512, 512, 256, 0, 0, 0, 1.0f, 0);

  for (int l = 0; l < 2; ++l) {
    // qkv + scatter into q_s / k_s / v_t
    gemm_bt<2, 2, MODE_QKV><<<dim3(6, 256, 1), dim3(256), 0, stream>>>(
        h16, wqkv16 + (size_t)l * 196608, bqkv + l * 768, q_s, k_s, v_t, 256,
        256, 256, 0, 0, 0, 0, 1.0f, 0);
    // fused flash attention -> o16 (merged [B*S, H*dh])
    attn_k<<<dim3(8, 128), dim3(256), 0, stream>>>(q_s, k_s, v_t, o16);
    // o-projection -> fp32 lin
    gemm_bt<2, 2, MODE_F32><<<dim3(2, 256, 1), dim3(256), 0, stream>>>(
        o16, wo16 + (size_t)l * 65536, bo + l * 256, lin, nullptr, nullptr,
        256, 256, 256, 256, 0, 0, 0, 1.0f, 0);
    // LN1(h + o)
    ln_k<<<dim3(8192), dim3(256), 0, stream>>>(h32, lin, g1 + l * 256,
                                               b1 + l * 256, h32, h16);
    // FF1 + relu
    gemm_bt<2, 2, MODE_BF16><<<dim3(8, 256, 1), dim3(256), 0, stream>>>(
        h16, w116 + (size_t)l * 262144, c1 + l * 1024, ff1, nullptr, nullptr,
        256, 256, 256, 1024, 0, 0, 0, 1.0f, 1);
    // FF2 -> fp32 lin
    gemm_bt<2, 2, MODE_F32><<<dim3(2, 256, 1), dim3(256), 0, stream>>>(
        ff1, w216 + (size_t)l * 262144, c2 + l * 256, lin, nullptr, nullptr,
        1024, 1024, 1024, 256, 0, 0, 0, 1.0f, 0);
    // LN2(x + ff); final layer writes fp32 straight to d_out
    float* y32 = (l == 1) ? (float*)d_out : h32;
    u16* y16 = (l == 1) ? nullptr : h16;
    ln_k<<<dim3(8192), dim3(256), 0, stream>>>(h32, lin, g2 + l * 256,
                                               b2 + l * 256, y32, y16);
  }
}